// Round 5
// baseline (8497.742 us; speedup 1.0000x reference)
//
#include <hip/hip_runtime.h>
#include <math.h>

#define BSZ 256
#define NV  4096
#define MC  2048
#define HID 1024
#define FREEN 512
#define NITER 31
#define TOLF 1e-4f
#define EPSF 1e-6f

typedef _Float16 half8 __attribute__((ext_vector_type(8)));
typedef _Float16 half4 __attribute__((ext_vector_type(4)));
typedef float f32x16 __attribute__((ext_vector_type(16)));

enum { EPI_NONE=0, EPI_BIASRELU=1, EPI_BIAS=2, EPI_ADDMAT=3, EPI_EQ=4, EPI_SUBMAT=5 };

// ---------------- f32 vector-ALU GEMM (prologue + fallback path) ----------------
template<int BM,int BN,int BK,int TM,int TN,bool TB,bool RELUIN,int EPI>
__global__ __launch_bounds__(256)
void gemm_k(const float* __restrict__ X, int ldx,
            const float* __restrict__ W, int ldw,
            float* __restrict__ C,
            int K, int N,
            const float* __restrict__ bvec,
            const float* __restrict__ addm, int ldadd,
            const int* __restrict__ guard)
{
  if (guard && guard[0]) return;
  const int t = (int)threadIdx.x;
  const int m0 = (int)blockIdx.y*BM, n0 = (int)blockIdx.x*BN;
  __shared__ float As[BK][BM+4];
  __shared__ float Bs[BK][BN+4];
  constexpr int TX = BN/TN;
  const int tx = t % TX, ty = t / TX;
  constexpr int ALD = (BM*BK)/1024;
  constexpr int BLD = (BN*BK)/1024;
  float4 pa[ALD], pb[BLD];
  float acc[TM][TN];
  #pragma unroll
  for (int i=0;i<TM;i++)
    #pragma unroll
    for (int j=0;j<TN;j++) acc[i][j]=0.f;

  const int nk = K/BK;

  auto loadA = [&](int kt){
    const int k0 = kt*BK;
    const bool rl = RELUIN && (k0 >= FREEN);
    #pragma unroll
    for (int q=0;q<ALD;q++){
      const int idx = q*256 + t;
      const int r = idx/(BK/4), c4 = (idx%(BK/4))*4;
      float4 v = *reinterpret_cast<const float4*>(&X[(size_t)(m0+r)*ldx + k0 + c4]);
      if (rl){ v.x=fmaxf(v.x,0.f); v.y=fmaxf(v.y,0.f); v.z=fmaxf(v.z,0.f); v.w=fmaxf(v.w,0.f); }
      pa[q]=v;
    }
  };
  auto loadB = [&](int kt){
    const int k0 = kt*BK;
    #pragma unroll
    for (int q=0;q<BLD;q++){
      const int idx = q*256 + t;
      if (TB){
        const int r = idx/(BK/4), c4 = (idx%(BK/4))*4;
        pb[q] = *reinterpret_cast<const float4*>(&W[(size_t)(n0+r)*ldw + k0 + c4]);
      } else {
        const int r = idx/(BN/4), c4 = (idx%(BN/4))*4;
        pb[q] = *reinterpret_cast<const float4*>(&W[(size_t)(k0+r)*ldw + n0 + c4]);
      }
    }
  };
  auto stor = [&](){
    #pragma unroll
    for (int q=0;q<ALD;q++){
      const int idx = q*256 + t;
      const int r = idx/(BK/4), c4 = (idx%(BK/4))*4;
      As[c4+0][r]=pa[q].x; As[c4+1][r]=pa[q].y; As[c4+2][r]=pa[q].z; As[c4+3][r]=pa[q].w;
    }
    #pragma unroll
    for (int q=0;q<BLD;q++){
      const int idx = q*256 + t;
      if (TB){
        const int r = idx/(BK/4), c4 = (idx%(BK/4))*4;
        Bs[c4+0][r]=pb[q].x; Bs[c4+1][r]=pb[q].y; Bs[c4+2][r]=pb[q].z; Bs[c4+3][r]=pb[q].w;
      } else {
        const int r = idx/(BN/4), c4 = (idx%(BN/4))*4;
        *reinterpret_cast<float4*>(&Bs[r][c4]) = pb[q];
      }
    }
  };

  loadA(0); loadB(0);
  for (int kt=0; kt<nk; ++kt){
    __syncthreads();
    stor();
    __syncthreads();
    if (kt+1 < nk){ loadA(kt+1); loadB(kt+1); }
    #pragma unroll
    for (int kk=0; kk<BK; ++kk){
      float a[TM], b[TN];
      if constexpr (TM==4) *reinterpret_cast<float4*>(a) = *reinterpret_cast<const float4*>(&As[kk][ty*TM]);
      else                 *reinterpret_cast<float2*>(a) = *reinterpret_cast<const float2*>(&As[kk][ty*TM]);
      if constexpr (TN==4) *reinterpret_cast<float4*>(b) = *reinterpret_cast<const float4*>(&Bs[kk][tx*TN]);
      else                 *reinterpret_cast<float2*>(b) = *reinterpret_cast<const float2*>(&Bs[kk][tx*TN]);
      #pragma unroll
      for (int i=0;i<TM;i++)
        #pragma unroll
        for (int j=0;j<TN;j++)
          acc[i][j] = fmaf(a[i], b[j], acc[i][j]);
    }
  }

  if constexpr (EPI==EPI_EQ){
    float csum[TN];
    #pragma unroll
    for (int j=0;j<TN;j++) csum[j]=0.f;
    #pragma unroll
    for (int i=0;i<TM;i++){
      const int r = m0 + ty*TM + i;
      #pragma unroll
      for (int j=0;j<TN;j++){
        const int c = n0 + tx*TN + j;
        const float v = acc[i][j] - addm[(size_t)r*ldadd + c];
        csum[j] += fabsf(v);
      }
    }
    __syncthreads();
    float* red = &As[0][0];
    constexpr int RY = BM/TM;
    #pragma unroll
    for (int j=0;j<TN;j++) red[(tx*TN+j)*RY + ty] = csum[j];
    __syncthreads();
    if (t < BN){
      float s=0.f;
      #pragma unroll
      for (int y=0;y<RY;y++) s += red[t*RY + y];
      C[(size_t)blockIdx.y*N + n0 + t] = s;
    }
  } else {
    #pragma unroll
    for (int i=0;i<TM;i++){
      const int r = m0 + ty*TM + i;
      #pragma unroll
      for (int j=0;j<TN;j++){
        const int c = n0 + tx*TN + j;
        float v = acc[i][j];
        if constexpr (EPI==EPI_BIASRELU){ v += bvec[c]; v = fmaxf(v,0.f); }
        if constexpr (EPI==EPI_BIAS)    { v += bvec[c]; }
        if constexpr (EPI==EPI_ADDMAT)  { v += addm[(size_t)r*ldadd + c]; }
        if constexpr (EPI==EPI_SUBMAT)  { v -= addm[(size_t)r*ldadd + c]; }
        C[(size_t)r*N + c] = v;
      }
    }
  }
}

// ---------------- fp16x2 split helpers ----------------
__device__ __forceinline__ void split_f32(float v, _Float16& h, _Float16& l){
  float hf = 0.f;
  _Float16 hh = (_Float16)0.f;
  if (fabsf(v) >= 6.103515625e-05f) { hh = (_Float16)v; hf = (float)hh; }
  h = hh;
  l = (_Float16)((v - hf) * 2048.0f);
}

__global__ __launch_bounds__(256)
void split_k(const float* __restrict__ src, _Float16* __restrict__ h,
             _Float16* __restrict__ l, int n4)
{
  const int i = blockIdx.x*256 + threadIdx.x;
  if (i >= n4) return;
  const float4 v = *reinterpret_cast<const float4*>(&src[(size_t)i*4]);
  half4 hh, ll;
  _Float16 a, b;
  split_f32(v.x,a,b); hh.x=a; ll.x=b;
  split_f32(v.y,a,b); hh.y=a; ll.y=b;
  split_f32(v.z,a,b); hh.z=a; ll.z=b;
  split_f32(v.w,a,b); hh.w=a; ll.w=b;
  *reinterpret_cast<half4*>(&h[(size_t)i*4]) = hh;
  *reinterpret_cast<half4*>(&l[(size_t)i*4]) = ll;
}

// transpose-convert: W [NV][MC] f32 row-major -> Wt [MC][NV] fp16 (hi only)
__global__ __launch_bounds__(256)
void trsplit_k(const float* __restrict__ W, _Float16* __restrict__ Wt)
{
  __shared__ float ts[64][65];
  const int t = (int)threadIdx.x;
  const int i0 = (int)blockIdx.x*64;   // k rows in W
  const int j0 = (int)blockIdx.y*64;   // c cols in W
  const int rr = t >> 4, cc = (t & 15)*4;
  #pragma unroll
  for (int p=0;p<4;p++){
    const int r = p*16 + rr;
    const float4 v = *reinterpret_cast<const float4*>(&W[(size_t)(i0+r)*MC + j0 + cc]);
    ts[r][cc+0]=v.x; ts[r][cc+1]=v.y; ts[r][cc+2]=v.z; ts[r][cc+3]=v.w;
  }
  __syncthreads();
  #pragma unroll
  for (int p=0;p<4;p++){
    const int orow = p*16 + rr;        // output row (c)
    half4 h;
    h.x = (_Float16)ts[cc+0][orow];
    h.y = (_Float16)ts[cc+1][orow];
    h.z = (_Float16)ts[cc+2][orow];
    h.w = (_Float16)ts[cc+3][orow];
    *reinterpret_cast<half4*>(&Wt[(size_t)(j0+orow)*NV + i0 + cc]) = h;
  }
}

// ---------------- fused fp16x2 MFMA dispatch ----------------
// Grid (64 or 96, 2, 4). x<64: PROJ tile (B = WzProj pair, 3-pass fp16x2) -> pp[kz].
//                        x>=64: EQ tile (B = Wbt hi-only, 1-pass) -> ppe[kz].
// All blocks: tile 128x64, K=1024 (16 k-tiles). 768 blocks = 3/CU, all resident.
template<bool RELU>
__global__ __launch_bounds__(256)
void fused16_k(const _Float16* __restrict__ zh, const _Float16* __restrict__ zl,
               const _Float16* __restrict__ Wzh, const _Float16* __restrict__ Wzl,
               const _Float16* __restrict__ Wbt,
               float* __restrict__ pp,    // [4][BSZ*NV]
               float* __restrict__ ppe,   // [4][BSZ*MC]
               const int* __restrict__ guard)
{
  if (guard[0]) return;
  const int tile = (int)blockIdx.x;
  const bool is_eq = tile >= 64;
  const int kz = (int)blockIdx.z;
  const int t = (int)threadIdx.x;
  const int m0 = (int)blockIdx.y * 128;
  const int n0 = is_eq ? (tile-64)*64 : tile*64;
  const int kbeg = kz * 1024;

  __shared__ _Float16 Ah[128][64], Al[128][64], Bh_s[64][64], Bl_s[64][64];

  const int lane = t & 63, wid = t >> 6;
  const int wr = wid >> 1, wc = wid & 1, lg = lane >> 5, ln = lane & 31;

  f32x16 a0[2], a1[2], a2[2];
  #pragma unroll
  for (int f=0; f<2; ++f)
    #pragma unroll
    for (int i=0;i<16;i++){ a0[f][i]=0.f; a1[f][i]=0.f; a2[f][i]=0.f; }

  float4 rAh[4], rAl[4], rBh[2], rBl[2];
  const _Float16* __restrict__ Bhg = is_eq ? Wbt : Wzh;

  auto gload = [&](int kt){
    const int k0 = kbeg + kt*64;
    #pragma unroll
    for (int q=0;q<4;q++){
      const int idx = q*256 + t;
      const int r = idx>>3, ch = idx&7;
      const size_t off = (size_t)(m0+r)*NV + k0 + ch*8;
      rAh[q] = *reinterpret_cast<const float4*>(&zh[off]);
      if (!is_eq) rAl[q] = *reinterpret_cast<const float4*>(&zl[off]);
    }
    #pragma unroll
    for (int q=0;q<2;q++){
      const int idx = q*256 + t;
      const int r = idx>>3, ch = idx&7;
      const size_t off = (size_t)(n0+r)*NV + k0 + ch*8;
      rBh[q] = *reinterpret_cast<const float4*>(&Bhg[off]);
      if (!is_eq) rBl[q] = *reinterpret_cast<const float4*>(&Wzl[off]);
    }
  };
  auto sstore = [&](int kt){
    const bool rl = RELU && (kbeg + kt*64 >= FREEN);
    #pragma unroll
    for (int q=0;q<4;q++){
      const int idx = q*256 + t;
      const int r = idx>>3, ch = idx&7;
      const int sc = (ch ^ (r&7))*8;
      if (is_eq){
        float4 vh = rAh[q];
        if (rl){
          half8 hh = *reinterpret_cast<half8*>(&vh);
          #pragma unroll
          for (int j=0;j<8;j++) if (hh[j] < (_Float16)0.f) hh[j] = (_Float16)0.f;
          vh = *reinterpret_cast<float4*>(&hh);
        }
        *reinterpret_cast<float4*>(&Ah[r][sc]) = vh;
      } else {
        float4 vh = rAh[q], vl = rAl[q];
        if (rl){
          half8 hh = *reinterpret_cast<half8*>(&vh);
          half8 ll = *reinterpret_cast<half8*>(&vl);
          #pragma unroll
          for (int j=0;j<8;j++){
            const _Float16 h = hh[j], l = ll[j];
            if (h < (_Float16)0.f || (h == (_Float16)0.f && l < (_Float16)0.f)){
              hh[j] = (_Float16)0.f; ll[j] = (_Float16)0.f;
            }
          }
          vh = *reinterpret_cast<float4*>(&hh);
          vl = *reinterpret_cast<float4*>(&ll);
        }
        *reinterpret_cast<float4*>(&Ah[r][sc]) = vh;
        *reinterpret_cast<float4*>(&Al[r][sc]) = vl;
      }
    }
    #pragma unroll
    for (int q=0;q<2;q++){
      const int idx = q*256 + t;
      const int r = idx>>3, ch = idx&7;
      const int sc = (ch ^ (r&7))*8;
      *reinterpret_cast<float4*>(&Bh_s[r][sc]) = rBh[q];
      if (!is_eq) *reinterpret_cast<float4*>(&Bl_s[r][sc]) = rBl[q];
    }
  };

  gload(0);
  for (int kt=0; kt<16; ++kt){
    __syncthreads();
    sstore(kt);
    __syncthreads();
    if (kt+1 < 16) gload(kt+1);
    const int brow = wc*32 + ln;
    #pragma unroll
    for (int s=0;s<4;s++){
      const int cb = ((s*2+lg) ^ (brow&7))*8;
      const half8 bh = *reinterpret_cast<const half8*>(&Bh_s[brow][cb]);
      if (is_eq){
        #pragma unroll
        for (int f=0; f<2; ++f){
          const int arow = wr*64 + f*32 + ln;
          const int ca = ((s*2+lg) ^ (arow&7))*8;
          const half8 ah = *reinterpret_cast<const half8*>(&Ah[arow][ca]);
          a0[f] = __builtin_amdgcn_mfma_f32_32x32x16_f16(ah, bh, a0[f], 0, 0, 0);
        }
      } else {
        const half8 bl = *reinterpret_cast<const half8*>(&Bl_s[brow][cb]);
        #pragma unroll
        for (int f=0; f<2; ++f){
          const int arow = wr*64 + f*32 + ln;
          const int ca = ((s*2+lg) ^ (arow&7))*8;
          const half8 ah = *reinterpret_cast<const half8*>(&Ah[arow][ca]);
          const half8 al = *reinterpret_cast<const half8*>(&Al[arow][ca]);
          a0[f] = __builtin_amdgcn_mfma_f32_32x32x16_f16(ah, bh, a0[f], 0, 0, 0);
          a1[f] = __builtin_amdgcn_mfma_f32_32x32x16_f16(ah, bl, a1[f], 0, 0, 0);
          a2[f] = __builtin_amdgcn_mfma_f32_32x32x16_f16(al, bh, a2[f], 0, 0, 0);
        }
      }
    }
  }

  if (is_eq){
    float* __restrict__ dst = ppe + (size_t)kz*BSZ*MC;
    #pragma unroll
    for (int f=0; f<2; ++f)
      #pragma unroll
      for (int r16=0;r16<16;r16++){
        const int row = (r16&3) + 8*(r16>>2) + 4*lg;   // verified 32x32 C/D mapping
        const int gm = m0 + wr*64 + f*32 + row;
        const int gn = n0 + wc*32 + ln;
        dst[(size_t)gm*MC + gn] = a0[f][r16];
      }
  } else {
    float* __restrict__ dst = pp + (size_t)kz*BSZ*NV;
    #pragma unroll
    for (int f=0; f<2; ++f)
      #pragma unroll
      for (int r16=0;r16<16;r16++){
        const int row = (r16&3) + 8*(r16>>2) + 4*lg;
        const int gm = m0 + wr*64 + f*32 + row;
        const int gn = n0 + wc*32 + ln;
        dst[(size_t)gm*NV + gn] = a0[f][r16] + (a1[f][r16]+a2[f][r16])*(1.f/2048.f);
      }
  }
}

// combine: z = sum4(pp) + Bias -> split pair + ineq column partials (16 row-groups)
__global__ __launch_bounds__(256)
void combine4_k(const float* __restrict__ pp, const float* __restrict__ BiasM,
                _Float16* __restrict__ zh, _Float16* __restrict__ zl,
                float* __restrict__ ineqpart, const int* __restrict__ guard)
{
  if (guard[0]) return;
  const int c = blockIdx.x*256 + threadIdx.x;
  const int rb = blockIdx.y;
  const size_t SZ = (size_t)BSZ*NV;
  float acc = 0.f;
  for (int r=0; r<16; ++r){
    const size_t idx = (size_t)(rb*16+r)*NV + c;
    const float z = pp[idx] + pp[SZ+idx] + pp[2*SZ+idx] + pp[3*SZ+idx] + BiasM[idx];
    _Float16 h, l; split_f32(z, h, l);
    zh[idx] = h; zl[idx] = l;
    acc += fmaxf(-z, 0.f);
  }
  ineqpart[(size_t)rb*NV + c] = acc;
}

// eq reduce: per-column partials of |BiasATmB + eps*sum4(ppe)| over 16-row groups
__global__ __launch_bounds__(256)
void eqred_k(const float* __restrict__ ppe, const float* __restrict__ BiasATmB,
             float* __restrict__ eqpart16, const int* __restrict__ guard)
{
  if (guard[0]) return;
  const int c = blockIdx.x*256 + threadIdx.x;
  const int rb = blockIdx.y;
  const size_t SE = (size_t)BSZ*MC;
  float s = 0.f;
  for (int r=0; r<16; ++r){
    const size_t idx = (size_t)(rb*16+r)*MC + c;
    const float v = BiasATmB[idx] + EPSF*(ppe[idx] + ppe[SE+idx] + ppe[2*SE+idx] + ppe[3*SE+idx]);
    s += fabsf(v);
  }
  eqpart16[(size_t)rb*MC + c] = s;
}

__global__ __launch_bounds__(256)
void check3_k(const float* __restrict__ eqpart16, const float* __restrict__ ineqpart,
              int* __restrict__ viol, const int* __restrict__ done)
{
  if (done[0]) return;
  const int id = blockIdx.x*256 + threadIdx.x;
  bool bad;
  if (id < MC){
    float s = 0.f;
    #pragma unroll
    for (int g=0; g<16; g++) s += eqpart16[(size_t)g*MC + id];
    bad = (s*(1.f/(float)BSZ) > TOLF);
  } else {
    const int c = FREEN + (id - MC);
    float s = 0.f;
    #pragma unroll
    for (int g=0; g<16; g++) s += ineqpart[(size_t)g*NV + c];
    bad = (s*(1.f/(float)BSZ) > TOLF);
  }
  if (bad) atomicAdd(viol, 1);
}

// ---------------- LayerNorm ----------------
__global__ __launch_bounds__(256)
void ln_k(float* __restrict__ x, const float* __restrict__ g, const float* __restrict__ b)
{
  const int row = blockIdx.x, t = threadIdx.x;
  float4 v = *reinterpret_cast<const float4*>(&x[(size_t)row*HID + t*4]);
  __shared__ float sm[256];
  sm[t] = v.x+v.y+v.z+v.w;
  __syncthreads();
  for (int st=128; st>0; st>>=1){ if (t<st) sm[t]+=sm[t+st]; __syncthreads(); }
  const float mu = sm[0]*(1.f/(float)HID);
  __syncthreads();
  const float dx=v.x-mu, dy=v.y-mu, dz=v.z-mu, dw=v.w-mu;
  sm[t] = dx*dx+dy*dy+dz*dz+dw*dw;
  __syncthreads();
  for (int st=128; st>0; st>>=1){ if (t<st) sm[t]+=sm[t+st]; __syncthreads(); }
  const float inv = 1.f/sqrtf(sm[0]*(1.f/(float)HID) + 1e-5f);
  const int c = t*4;
  const float4 gv = *reinterpret_cast<const float4*>(&g[c]);
  const float4 bv = *reinterpret_cast<const float4*>(&b[c]);
  float4 o;
  o.x = dx*inv*gv.x + bv.x; o.y = dy*inv*gv.y + bv.y;
  o.z = dz*inv*gv.z + bv.z; o.w = dw*inv*gv.w + bv.w;
  *reinterpret_cast<float4*>(&x[(size_t)row*HID + c]) = o;
}

// ---------------- fallback convergence machinery (f32 path) ----------------
__global__ __launch_bounds__(256)
void check_k(const float* __restrict__ eqpart, const float* __restrict__ znew,
             int* __restrict__ viol, const int* __restrict__ done, int ngroups)
{
  if (done[0]) return;
  const int id = blockIdx.x*256 + threadIdx.x;
  bool bad;
  if (id < MC){
    float s = 0.f;
    for (int g=0; g<ngroups; g++) s += eqpart[g*MC + id];
    bad = (s*(1.f/(float)BSZ) > TOLF);
  } else {
    const int c = FREEN + (id - MC);
    float s = 0.f;
    for (int r=0; r<BSZ; r++){
      const float v = znew[(size_t)r*NV + c];
      s += (v < 0.f) ? -v : 0.f;
    }
    bad = (s*(1.f/(float)BSZ) > TOLF);
  }
  if (bad) atomicAdd(viol, 1);
}

__global__ void init_k(int* flags){ flags[0]=0; flags[1]=0; flags[2]=0; }

__global__ void update_k(int* flags){
  if (!flags[0]){ flags[1] += 1; if (flags[2]==0) flags[0]=1; }
  flags[2] = 0;
}

__global__ __launch_bounds__(256)
void final_k(const float* __restrict__ buf1, float* __restrict__ out, const int* __restrict__ flags)
{
  const int i = blockIdx.x*256 + threadIdx.x;
  const int k = flags[1];
  if ((k & 1) && i < BSZ*NV) out[i] = buf1[i];
  if (i == 0) out[2*BSZ*NV] = (float)k;
}

__global__ __launch_bounds__(256)
void final16_k(const _Float16* __restrict__ zh0, const _Float16* __restrict__ zl0,
               const _Float16* __restrict__ zh1, const _Float16* __restrict__ zl1,
               float* __restrict__ out, const int* __restrict__ flags)
{
  const int i = blockIdx.x*256 + threadIdx.x;
  const int k = flags[1];
  const _Float16* h = (k & 1) ? zh1 : zh0;
  const _Float16* l = (k & 1) ? zl1 : zl0;
  out[i] = (float)h[i] + (float)l[i]*(1.f/2048.f);
  if (i == 0) out[2*BSZ*NV] = (float)k;
}

// ---------------- host launch ----------------
extern "C" void kernel_launch(void* const* d_in, const int* in_sizes, int n_in,
                              void* d_out, int out_size, void* d_ws, size_t ws_size,
                              hipStream_t stream)
{
  const float* bp  = (const float*)d_in[0];
  const float* w1  = (const float*)d_in[1];
  const float* b1  = (const float*)d_in[2];
  const float* g1  = (const float*)d_in[3];
  const float* be1 = (const float*)d_in[4];
  const float* w2  = (const float*)d_in[5];
  const float* b2  = (const float*)d_in[6];
  const float* g2  = (const float*)d_in[7];
  const float* be2 = (const float*)d_in[8];
  const float* w3  = (const float*)d_in[9];
  const float* b3  = (const float*)d_in[10];
  const float* g3  = (const float*)d_in[11];
  const float* be3 = (const float*)d_in[12];
  const float* wo  = (const float*)d_in[13];
  const float* bo  = (const float*)d_in[14];
  const float* A   = (const float*)d_in[15];
  const float* Wz  = (const float*)d_in[16];
  const float* Wb  = (const float*)d_in[17];

  float* out  = (float*)d_out;
  float* z0   = out + (size_t)BSZ*NV;
  float* buf0 = out;

  float* ws        = (float*)d_ws;
  float* tmp1      = ws;                              // 256*1024
  float* tmp2      = tmp1 + (size_t)BSZ*HID;          // 256*1024
  float* BiasM     = tmp2 + (size_t)BSZ*HID;          // 256*4096
  float* ineqpart  = BiasM + (size_t)BSZ*NV;          // 16*4096
  float* pp        = ineqpart + (size_t)16*NV;        // 4*256*4096
  float* ppe       = pp + (size_t)4*BSZ*NV;           // 4*256*2048
  float* BiasATmB  = ppe + (size_t)4*BSZ*MC;          // 256*2048
  float* eqpart16  = BiasATmB + (size_t)BSZ*MC;       // 16*2048
  int*   flags     = (int*)(eqpart16 + (size_t)16*MC);// 4 ints
  float* fbArea    = (float*)(flags + 4);
  // fallback-only (aliased by fp16 region):
  float* buf1      = fbArea;                          // 256*4096
  float* eqpartFB  = buf1 + (size_t)BSZ*NV;           // 8*2048
  // fp16-only (aliases fbArea):
  _Float16* Wzh = (_Float16*)fbArea;
  _Float16* Wzl = Wzh + (size_t)NV*NV;
  _Float16* Wbt = Wzl + (size_t)NV*NV;                // [MC][NV]
  _Float16* zh0 = Wbt + (size_t)MC*NV;
  _Float16* zl0 = zh0 + (size_t)BSZ*NV;
  _Float16* zh1 = zl0 + (size_t)BSZ*NV;
  _Float16* zl1 = zh1 + (size_t)BSZ*NV;
  const size_t need = (size_t)((char*)(zl1 + (size_t)BSZ*NV) - (char*)d_ws);
  const bool fp16path = (ws_size >= need);

  const dim3 blk(256);

  hipLaunchKernelGGL(init_k, dim3(1), dim3(1), 0, stream, flags);

  // ---- MLP (f32, one-time) ----
  hipLaunchKernelGGL((gemm_k<64,64,32,4,4,false,false,EPI_BIASRELU>), dim3(HID/64, BSZ/64), blk, 0, stream,
                     bp, MC, w1, HID, tmp1, MC, HID, b1, nullptr, 0, nullptr);
  hipLaunchKernelGGL(ln_k, dim3(BSZ), blk, 0, stream, tmp1, g1, be1);
  hipLaunchKernelGGL((gemm_k<64,64,32,4,4,false,false,EPI_BIASRELU>), dim3(HID/64, BSZ/64), blk, 0, stream,
                     tmp1, HID, w2, HID, tmp2, HID, HID, b2, nullptr, 0, nullptr);
  hipLaunchKernelGGL(ln_k, dim3(BSZ), blk, 0, stream, tmp2, g2, be2);
  hipLaunchKernelGGL((gemm_k<64,64,32,4,4,false,false,EPI_BIASRELU>), dim3(HID/64, BSZ/64), blk, 0, stream,
                     tmp2, HID, w3, HID, tmp1, HID, HID, b3, nullptr, 0, nullptr);
  hipLaunchKernelGGL(ln_k, dim3(BSZ), blk, 0, stream, tmp1, g3, be3);
  hipLaunchKernelGGL((gemm_k<64,64,32,4,4,false,false,EPI_BIAS>), dim3(NV/64, BSZ/64), blk, 0, stream,
                     tmp1, HID, wo, NV, z0, HID, NV, bo, nullptr, 0, nullptr);
  // Bias = b_primal @ WbProj^T
  hipLaunchKernelGGL((gemm_k<64,64,32,4,4,true,false,EPI_NONE>), dim3(NV/64, BSZ/64), blk, 0, stream,
                     bp, MC, Wb, MC, BiasM, MC, NV, nullptr, nullptr, 0, nullptr);

  if (fp16path){
    // BiasATmB = Bias @ A^T - b  (constant across iterations)
    hipLaunchKernelGGL((gemm_k<64,64,32,4,4,true,false,EPI_SUBMAT>), dim3(MC/64, BSZ/64), blk, 0, stream,
                       BiasM, NV, A, NV, BiasATmB, NV, MC, nullptr, bp, MC, nullptr);
    // one-time fp16 conversions
    hipLaunchKernelGGL(split_k, dim3((NV*(size_t)NV)/1024), blk, 0, stream, Wz, Wzh, Wzl, (int)((NV*(size_t)NV)/4));
    hipLaunchKernelGGL(trsplit_k, dim3(NV/64, MC/64), blk, 0, stream, Wb, Wbt);
    hipLaunchKernelGGL(split_k, dim3((BSZ*(size_t)NV)/1024), blk, 0, stream, z0, zh1, zl1, (int)((BSZ*(size_t)NV)/4));

    // z_init = Bias + z0 @ Wp  (no relu, proj tiles only)
    hipLaunchKernelGGL((fused16_k<false>), dim3(64, 2, 4), blk, 0, stream,
                       zh1, zl1, Wzh, Wzl, Wbt, pp, ppe, flags);
    hipLaunchKernelGGL(combine4_k, dim3(NV/256, 16), blk, 0, stream,
                       pp, BiasM, zh0, zl0, ineqpart, flags);

    for (int j=1; j<=NITER; ++j){
      const _Float16* sh = ((j-1)&1) ? zh1 : zh0;
      const _Float16* sl = ((j-1)&1) ? zl1 : zl0;
      _Float16* dh = (j&1) ? zh1 : zh0;
      _Float16* dl = (j&1) ? zl1 : zl0;
      // proj partials (z_j) + eq partials (eq of z_j via identity), both from P2(z_{j-1})
      hipLaunchKernelGGL((fused16_k<true>), dim3(96, 2, 4), blk, 0, stream,
                         sh, sl, Wzh, Wzl, Wbt, pp, ppe, flags);
      hipLaunchKernelGGL(combine4_k, dim3(NV/256, 16), blk, 0, stream,
                         pp, BiasM, dh, dl, ineqpart, flags);
      hipLaunchKernelGGL(eqred_k, dim3(MC/256, 16), blk, 0, stream,
                         ppe, BiasATmB, eqpart16, flags);
      hipLaunchKernelGGL(check3_k, dim3((MC + (NV-FREEN))/256), blk, 0, stream,
                         eqpart16, ineqpart, flags+2, flags);
      hipLaunchKernelGGL(update_k, dim3(1), dim3(1), 0, stream, flags);
    }
    hipLaunchKernelGGL(final16_k, dim3((BSZ*NV)/256), blk, 0, stream, zh0, zl0, zh1, zl1, out, flags);
  } else {
    // fallback: proven f32 loop
    hipLaunchKernelGGL((gemm_k<64,64,32,4,4,true,false,EPI_ADDMAT>), dim3(NV/64, BSZ/64), blk, 0, stream,
                       z0, NV, Wz, NV, buf0, NV, NV, nullptr, BiasM, NV, nullptr);
    for (int j=1; j<=NITER; ++j){
      float* src = (j&1) ? buf0 : buf1;
      float* dst = (j&1) ? buf1 : buf0;
      hipLaunchKernelGGL((gemm_k<64,64,32,4,4,true,true,EPI_ADDMAT>), dim3(NV/64, BSZ/64), blk, 0, stream,
                         src, NV, Wz, NV, dst, NV, NV, nullptr, BiasM, NV, flags);
      hipLaunchKernelGGL((gemm_k<32,64,32,2,4,true,false,EPI_EQ>), dim3(MC/64, BSZ/32), blk, 0, stream,
                         dst, NV, A, NV, eqpartFB, NV, MC, nullptr, bp, MC, flags);
      hipLaunchKernelGGL(check_k, dim3((MC + (NV-FREEN))/256), blk, 0, stream, eqpartFB, dst, flags+2, flags, 8);
      hipLaunchKernelGGL(update_k, dim3(1), dim3(1), 0, stream, flags);
    }
    hipLaunchKernelGGL(final_k, dim3((BSZ*NV)/256), blk, 0, stream, buf1, out, flags);
  }

  (void)in_sizes; (void)n_in; (void)out_size; (void)ws_size;
}

// Round 6
// 4328.245 us; speedup vs baseline: 1.9633x; 1.9633x over previous
//
#include <hip/hip_runtime.h>
#include <math.h>

#define BSZ 256
#define NV  4096
#define MC  2048
#define HID 1024
#define FREEN 512
#define NITER 31
#define TOLF 1e-4f
#define EPSF 1e-6f
#define INV2048 4.8828125e-4f

typedef _Float16 half8 __attribute__((ext_vector_type(8)));
typedef _Float16 half4 __attribute__((ext_vector_type(4)));
typedef float f32x16 __attribute__((ext_vector_type(16)));

enum { EPI_NONE=0, EPI_BIASRELU=1, EPI_BIAS=2, EPI_ADDMAT=3, EPI_EQ=4, EPI_SUBMAT=5 };

// ---------------- f32 vector-ALU GEMM (prologue + fallback path) ----------------
template<int BM,int BN,int BK,int TM,int TN,bool TB,bool RELUIN,int EPI>
__global__ __launch_bounds__(256)
void gemm_k(const float* __restrict__ X, int ldx,
            const float* __restrict__ W, int ldw,
            float* __restrict__ C,
            int K, int N,
            const float* __restrict__ bvec,
            const float* __restrict__ addm, int ldadd,
            const int* __restrict__ guard)
{
  if (guard && guard[0]) return;
  const int t = (int)threadIdx.x;
  const int m0 = (int)blockIdx.y*BM, n0 = (int)blockIdx.x*BN;
  __shared__ float As[BK][BM+4];
  __shared__ float Bs[BK][BN+4];
  constexpr int TX = BN/TN;
  const int tx = t % TX, ty = t / TX;
  constexpr int ALD = (BM*BK)/1024;
  constexpr int BLD = (BN*BK)/1024;
  float4 pa[ALD], pb[BLD];
  float acc[TM][TN];
  #pragma unroll
  for (int i=0;i<TM;i++)
    #pragma unroll
    for (int j=0;j<TN;j++) acc[i][j]=0.f;

  const int nk = K/BK;

  auto loadA = [&](int kt){
    const int k0 = kt*BK;
    const bool rl = RELUIN && (k0 >= FREEN);
    #pragma unroll
    for (int q=0;q<ALD;q++){
      const int idx = q*256 + t;
      const int r = idx/(BK/4), c4 = (idx%(BK/4))*4;
      float4 v = *reinterpret_cast<const float4*>(&X[(size_t)(m0+r)*ldx + k0 + c4]);
      if (rl){ v.x=fmaxf(v.x,0.f); v.y=fmaxf(v.y,0.f); v.z=fmaxf(v.z,0.f); v.w=fmaxf(v.w,0.f); }
      pa[q]=v;
    }
  };
  auto loadB = [&](int kt){
    const int k0 = kt*BK;
    #pragma unroll
    for (int q=0;q<BLD;q++){
      const int idx = q*256 + t;
      if (TB){
        const int r = idx/(BK/4), c4 = (idx%(BK/4))*4;
        pb[q] = *reinterpret_cast<const float4*>(&W[(size_t)(n0+r)*ldw + k0 + c4]);
      } else {
        const int r = idx/(BN/4), c4 = (idx%(BN/4))*4;
        pb[q] = *reinterpret_cast<const float4*>(&W[(size_t)(k0+r)*ldw + n0 + c4]);
      }
    }
  };
  auto stor = [&](){
    #pragma unroll
    for (int q=0;q<ALD;q++){
      const int idx = q*256 + t;
      const int r = idx/(BK/4), c4 = (idx%(BK/4))*4;
      As[c4+0][r]=pa[q].x; As[c4+1][r]=pa[q].y; As[c4+2][r]=pa[q].z; As[c4+3][r]=pa[q].w;
    }
    #pragma unroll
    for (int q=0;q<BLD;q++){
      const int idx = q*256 + t;
      if (TB){
        const int r = idx/(BK/4), c4 = (idx%(BK/4))*4;
        Bs[c4+0][r]=pb[q].x; Bs[c4+1][r]=pb[q].y; Bs[c4+2][r]=pb[q].z; Bs[c4+3][r]=pb[q].w;
      } else {
        const int r = idx/(BN/4), c4 = (idx%(BN/4))*4;
        *reinterpret_cast<float4*>(&Bs[r][c4]) = pb[q];
      }
    }
  };

  loadA(0); loadB(0);
  for (int kt=0; kt<nk; ++kt){
    __syncthreads();
    stor();
    __syncthreads();
    if (kt+1 < nk){ loadA(kt+1); loadB(kt+1); }
    #pragma unroll
    for (int kk=0; kk<BK; ++kk){
      float a[TM], b[TN];
      if constexpr (TM==4) *reinterpret_cast<float4*>(a) = *reinterpret_cast<const float4*>(&As[kk][ty*TM]);
      else                 *reinterpret_cast<float2*>(a) = *reinterpret_cast<const float2*>(&As[kk][ty*TM]);
      if constexpr (TN==4) *reinterpret_cast<float4*>(b) = *reinterpret_cast<const float4*>(&Bs[kk][tx*TN]);
      else                 *reinterpret_cast<float2*>(b) = *reinterpret_cast<const float2*>(&Bs[kk][tx*TN]);
      #pragma unroll
      for (int i=0;i<TM;i++)
        #pragma unroll
        for (int j=0;j<TN;j++)
          acc[i][j] = fmaf(a[i], b[j], acc[i][j]);
    }
  }

  if constexpr (EPI==EPI_EQ){
    float csum[TN];
    #pragma unroll
    for (int j=0;j<TN;j++) csum[j]=0.f;
    #pragma unroll
    for (int i=0;i<TM;i++){
      const int r = m0 + ty*TM + i;
      #pragma unroll
      for (int j=0;j<TN;j++){
        const int c = n0 + tx*TN + j;
        const float v = acc[i][j] - addm[(size_t)r*ldadd + c];
        csum[j] += fabsf(v);
      }
    }
    __syncthreads();
    float* red = &As[0][0];
    constexpr int RY = BM/TM;
    #pragma unroll
    for (int j=0;j<TN;j++) red[(tx*TN+j)*RY + ty] = csum[j];
    __syncthreads();
    if (t < BN){
      float s=0.f;
      #pragma unroll
      for (int y=0;y<RY;y++) s += red[t*RY + y];
      C[(size_t)blockIdx.y*N + n0 + t] = s;
    }
  } else {
    #pragma unroll
    for (int i=0;i<TM;i++){
      const int r = m0 + ty*TM + i;
      #pragma unroll
      for (int j=0;j<TN;j++){
        const int c = n0 + tx*TN + j;
        float v = acc[i][j];
        if constexpr (EPI==EPI_BIASRELU){ v += bvec[c]; v = fmaxf(v,0.f); }
        if constexpr (EPI==EPI_BIAS)    { v += bvec[c]; }
        if constexpr (EPI==EPI_ADDMAT)  { v += addm[(size_t)r*ldadd + c]; }
        if constexpr (EPI==EPI_SUBMAT)  { v -= addm[(size_t)r*ldadd + c]; }
        C[(size_t)r*N + c] = v;
      }
    }
  }
}

// ---------------- fp16x2 split helpers ----------------
__device__ __forceinline__ void split_f32(float v, _Float16& h, _Float16& l){
  float hf = 0.f;
  _Float16 hh = (_Float16)0.f;
  if (fabsf(v) >= 6.103515625e-05f) { hh = (_Float16)v; hf = (float)hh; }
  h = hh;
  l = (_Float16)((v - hf) * 2048.0f);
}

__global__ __launch_bounds__(256)
void split_k(const float* __restrict__ src, _Float16* __restrict__ h,
             _Float16* __restrict__ l, int n4)
{
  const int i = blockIdx.x*256 + threadIdx.x;
  if (i >= n4) return;
  const float4 v = *reinterpret_cast<const float4*>(&src[(size_t)i*4]);
  half4 hh, ll;
  _Float16 a, b;
  split_f32(v.x,a,b); hh.x=a; ll.x=b;
  split_f32(v.y,a,b); hh.y=a; ll.y=b;
  split_f32(v.z,a,b); hh.z=a; ll.z=b;
  split_f32(v.w,a,b); hh.w=a; ll.w=b;
  *reinterpret_cast<half4*>(&h[(size_t)i*4]) = hh;
  *reinterpret_cast<half4*>(&l[(size_t)i*4]) = ll;
}

// transpose-convert: W [NV][MC] f32 row-major -> Wt [MC][NV] fp16 (hi only)
__global__ __launch_bounds__(256)
void trsplit_k(const float* __restrict__ W, _Float16* __restrict__ Wt)
{
  __shared__ float ts[64][65];
  const int t = (int)threadIdx.x;
  const int i0 = (int)blockIdx.x*64;
  const int j0 = (int)blockIdx.y*64;
  const int rr = t >> 4, cc = (t & 15)*4;
  #pragma unroll
  for (int p=0;p<4;p++){
    const int r = p*16 + rr;
    const float4 v = *reinterpret_cast<const float4*>(&W[(size_t)(i0+r)*MC + j0 + cc]);
    ts[r][cc+0]=v.x; ts[r][cc+1]=v.y; ts[r][cc+2]=v.z; ts[r][cc+3]=v.w;
  }
  __syncthreads();
  #pragma unroll
  for (int p=0;p<4;p++){
    const int orow = p*16 + rr;
    half4 h;
    h.x = (_Float16)ts[cc+0][orow];
    h.y = (_Float16)ts[cc+1][orow];
    h.z = (_Float16)ts[cc+2][orow];
    h.w = (_Float16)ts[cc+3][orow];
    *reinterpret_cast<half4*>(&Wt[(size_t)(j0+orow)*NV + i0 + cc]) = h;
  }
}

// ---------------- m97-style fused MFMA kernel ----------------
// Proj blocks (bid < 64*projKz): ext-K = [A=Ah,B=Wzl | A=Al,B=Wzh | A=Ah,B=Wzh] (12288),
//   single acc chain: cross part accumulated at x2048 scale, acc*=1/2048 at the 8192
//   boundary, then hh part at scale 1. Partial -> pp[kz].
// Eq blocks (64): A=Ah, B=Wbt, K=4096 split in 2 -> ppe[kz].
// Tile 128x128, BK=32, 4 waves (2x2), wave = 2x2 frags of 32x32x16; LDS dbuf 32KB;
// staging via global_load_lds width 16 (linear LDS, wave-uniform dest).
__global__ __launch_bounds__(256)
void fusedm_k(const _Float16* __restrict__ Ahg, const _Float16* __restrict__ Alg,
              const _Float16* __restrict__ Wzh, const _Float16* __restrict__ Wzl,
              const _Float16* __restrict__ Wbt,
              float* __restrict__ pp, float* __restrict__ ppe,
              int projKz, const int* __restrict__ guard)
{
  if (guard[0]) return;
  __shared__ _Float16 lds[2][8192];   // [buf][A 128x32 | B 128x32]
  const int t = (int)threadIdx.x;
  const int lane = t & 63, wid = t >> 6;
  const int wr = wid >> 1, wc = wid & 1;
  const int ln = lane & 31, lg = lane >> 5;

  const int bid = (int)blockIdx.x;
  const int nProj = 64*projKz;
  const bool is_eq = bid >= nProj;
  int kz, mt, nt, nsteps, scaleStep, loExt;
  if (!is_eq){
    kz = bid % projKz;
    mt = (bid / projKz) & 1;
    nt = bid / (2*projKz);
    const int chunk = 12288 / projKz;
    loExt = kz * chunk;
    nsteps = chunk / 32;
    const int ss = (8192 - loExt) / 32;
    scaleStep = ss < 0 ? 0 : ss;
  } else {
    const int e = bid - nProj;          // [0,64)
    kz = e & 1; mt = (e>>1)&1; nt = e>>2;
    loExt = 0; nsteps = 64; scaleStep = -1;
  }
  const int m0 = mt*128, n0 = nt*128;

  f32x16 acc[2][2];
  #pragma unroll
  for (int fm=0;fm<2;fm++)
    #pragma unroll
    for (int fn=0;fn<2;fn++)
      #pragma unroll
      for (int r=0;r<16;r++) acc[fm][fn][r] = 0.f;

  auto stage = [&](int i, int buf){
    const _Float16* aB; const _Float16* bB; int kk;
    if (is_eq){
      aB = Ahg; bB = Wbt; kk = kz*2048 + i*32;
    } else {
      const int gext = loExt + i*32;
      if (gext < 4096)      { aB = Ahg; bB = Wzl; kk = gext; }
      else if (gext < 8192) { aB = Alg; bB = Wzh; kk = gext - 4096; }
      else                  { aB = Ahg; bB = Wzh; kk = gext - 8192; }
    }
    _Float16* base = &lds[buf][0];
    const int r = (wid<<5) + (lane>>2);      // + q*16 below
    const int kadd = kk + ((lane&3)<<3);
    #pragma unroll
    for (int q=0;q<2;q++){
      const _Float16* ga = aB + (size_t)(m0 + r + q*16)*NV + kadd;
      __builtin_amdgcn_global_load_lds(
        (const __attribute__((address_space(1))) void*)ga,
        (__attribute__((address_space(3))) void*)(base + wid*1024 + q*512), 16, 0, 0);
      const _Float16* gb = bB + (size_t)(n0 + r + q*16)*NV + kadd;
      __builtin_amdgcn_global_load_lds(
        (const __attribute__((address_space(1))) void*)gb,
        (__attribute__((address_space(3))) void*)(base + 4096 + wid*1024 + q*512), 16, 0, 0);
    }
  };

  int cur = 0;
  stage(0, 0);
  __syncthreads();
  for (int i=0; i<nsteps; ++i){
    if (i+1 < nsteps) stage(i+1, cur^1);
    const _Float16* As = &lds[cur][0];
    const _Float16* Bs = &lds[cur][4096];
    half8 a[2][2], b[2][2];
    #pragma unroll
    for (int fm=0; fm<2; ++fm){
      const int row = wr*64 + fm*32 + ln;
      #pragma unroll
      for (int ks=0; ks<2; ++ks)
        a[fm][ks] = *reinterpret_cast<const half8*>(&As[row*32 + lg*8 + ks*16]);
    }
    #pragma unroll
    for (int fn=0; fn<2; ++fn){
      const int row = wc*64 + fn*32 + ln;
      #pragma unroll
      for (int ks=0; ks<2; ++ks)
        b[fn][ks] = *reinterpret_cast<const half8*>(&Bs[row*32 + lg*8 + ks*16]);
    }
    if (!is_eq && i == scaleStep){
      #pragma unroll
      for (int fm=0;fm<2;fm++)
        #pragma unroll
        for (int fn=0;fn<2;fn++)
          #pragma unroll
          for (int r=0;r<16;r++) acc[fm][fn][r] *= INV2048;
    }
    #pragma unroll
    for (int ks=0; ks<2; ++ks)
      #pragma unroll
      for (int fm=0; fm<2; ++fm)
        #pragma unroll
        for (int fn=0; fn<2; ++fn)
          acc[fm][fn] = __builtin_amdgcn_mfma_f32_32x32x16_f16(a[fm][ks], b[fn][ks], acc[fm][fn], 0, 0, 0);
    __syncthreads();
    cur ^= 1;
  }
  if (!is_eq && scaleStep >= nsteps){
    #pragma unroll
    for (int fm=0;fm<2;fm++)
      #pragma unroll
      for (int fn=0;fn<2;fn++)
        #pragma unroll
        for (int r=0;r<16;r++) acc[fm][fn][r] *= INV2048;
  }

  if (is_eq){
    float* __restrict__ dst = ppe + (size_t)kz*BSZ*MC;
    #pragma unroll
    for (int fm=0; fm<2; ++fm)
      #pragma unroll
      for (int fn=0; fn<2; ++fn)
        #pragma unroll
        for (int r=0; r<16; ++r){
          const int row = (r&3) + 8*(r>>2) + 4*lg;   // verified 32x32 C/D mapping
          const int gm = m0 + wr*64 + fm*32 + row;
          const int gn = n0 + wc*64 + fn*32 + ln;
          dst[(size_t)gm*MC + gn] = acc[fm][fn][r];
        }
  } else {
    float* __restrict__ dst = pp + (size_t)kz*BSZ*NV;
    #pragma unroll
    for (int fm=0; fm<2; ++fm)
      #pragma unroll
      for (int fn=0; fn<2; ++fn)
        #pragma unroll
        for (int r=0; r<16; ++r){
          const int row = (r&3) + 8*(r>>2) + 4*lg;
          const int gm = m0 + wr*64 + fm*32 + row;
          const int gn = n0 + wc*64 + fn*32 + ln;
          dst[(size_t)gm*NV + gn] = acc[fm][fn][r];
        }
  }
}

// combine: z = sum_ng(pp) + Bias -> z f32 (single buffer, freeze-safe),
//          rz pair = split(P2(z)), ineq column partials (16 row-groups)
__global__ __launch_bounds__(256)
void combineN_k(const float* __restrict__ pp, const float* __restrict__ BiasM,
                float* __restrict__ zout, _Float16* __restrict__ rzh,
                _Float16* __restrict__ rzl, float* __restrict__ ineqpart,
                int ng, const int* __restrict__ guard)
{
  if (guard[0]) return;
  const int c = blockIdx.x*256 + threadIdx.x;
  const int rb = blockIdx.y;
  const size_t SZ = (size_t)BSZ*NV;
  float acc = 0.f;
  for (int r=0; r<16; ++r){
    const size_t idx = (size_t)(rb*16+r)*NV + c;
    float z = BiasM[idx];
    for (int g=0; g<ng; ++g) z += pp[(size_t)g*SZ + idx];
    zout[idx] = z;
    const float rz = (c >= FREEN) ? fmaxf(z, 0.f) : z;
    _Float16 h, l; split_f32(rz, h, l);
    rzh[idx] = h; rzl[idx] = l;
    acc += fmaxf(-z, 0.f);
  }
  ineqpart[(size_t)rb*NV + c] = acc;
}

// eq reduce: per-column partials of |BiasATmB + eps*(ppe0+ppe1)| over 16-row groups
__global__ __launch_bounds__(256)
void eqred2_k(const float* __restrict__ ppe, const float* __restrict__ BiasATmB,
              float* __restrict__ eqpart16, const int* __restrict__ guard)
{
  if (guard[0]) return;
  const int c = blockIdx.x*256 + threadIdx.x;
  const int rb = blockIdx.y;
  const size_t SE = (size_t)BSZ*MC;
  float s = 0.f;
  for (int r=0; r<16; ++r){
    const size_t idx = (size_t)(rb*16+r)*MC + c;
    const float v = BiasATmB[idx] + EPSF*(ppe[idx] + ppe[SE+idx]);
    s += fabsf(v);
  }
  eqpart16[(size_t)rb*MC + c] = s;
}

__global__ __launch_bounds__(256)
void check3_k(const float* __restrict__ eqpart16, const float* __restrict__ ineqpart,
              int* __restrict__ viol, const int* __restrict__ done)
{
  if (done[0]) return;
  const int id = blockIdx.x*256 + threadIdx.x;
  bool bad;
  if (id < MC){
    float s = 0.f;
    #pragma unroll
    for (int g=0; g<16; g++) s += eqpart16[(size_t)g*MC + id];
    bad = (s*(1.f/(float)BSZ) > TOLF);
  } else {
    const int c = FREEN + (id - MC);
    float s = 0.f;
    #pragma unroll
    for (int g=0; g<16; g++) s += ineqpart[(size_t)g*NV + c];
    bad = (s*(1.f/(float)BSZ) > TOLF);
  }
  if (bad) atomicAdd(viol, 1);
}

// ---------------- LayerNorm ----------------
__global__ __launch_bounds__(256)
void ln_k(float* __restrict__ x, const float* __restrict__ g, const float* __restrict__ b)
{
  const int row = blockIdx.x, t = threadIdx.x;
  float4 v = *reinterpret_cast<const float4*>(&x[(size_t)row*HID + t*4]);
  __shared__ float sm[256];
  sm[t] = v.x+v.y+v.z+v.w;
  __syncthreads();
  for (int st=128; st>0; st>>=1){ if (t<st) sm[t]+=sm[t+st]; __syncthreads(); }
  const float mu = sm[0]*(1.f/(float)HID);
  __syncthreads();
  const float dx=v.x-mu, dy=v.y-mu, dz=v.z-mu, dw=v.w-mu;
  sm[t] = dx*dx+dy*dy+dz*dz+dw*dw;
  __syncthreads();
  for (int st=128; st>0; st>>=1){ if (t<st) sm[t]+=sm[t+st]; __syncthreads(); }
  const float inv = 1.f/sqrtf(sm[0]*(1.f/(float)HID) + 1e-5f);
  const int c = t*4;
  const float4 gv = *reinterpret_cast<const float4*>(&g[c]);
  const float4 bv = *reinterpret_cast<const float4*>(&b[c]);
  float4 o;
  o.x = dx*inv*gv.x + bv.x; o.y = dy*inv*gv.y + bv.y;
  o.z = dz*inv*gv.z + bv.z; o.w = dw*inv*gv.w + bv.w;
  *reinterpret_cast<float4*>(&x[(size_t)row*HID + c]) = o;
}

// ---------------- flags / fallback machinery ----------------
__global__ __launch_bounds__(256)
void check_k(const float* __restrict__ eqpart, const float* __restrict__ znew,
             int* __restrict__ viol, const int* __restrict__ done, int ngroups)
{
  if (done[0]) return;
  const int id = blockIdx.x*256 + threadIdx.x;
  bool bad;
  if (id < MC){
    float s = 0.f;
    for (int g=0; g<ngroups; g++) s += eqpart[g*MC + id];
    bad = (s*(1.f/(float)BSZ) > TOLF);
  } else {
    const int c = FREEN + (id - MC);
    float s = 0.f;
    for (int r=0; r<BSZ; r++){
      const float v = znew[(size_t)r*NV + c];
      s += (v < 0.f) ? -v : 0.f;
    }
    bad = (s*(1.f/(float)BSZ) > TOLF);
  }
  if (bad) atomicAdd(viol, 1);
}

__global__ void init_k(int* flags){ flags[0]=0; flags[1]=0; flags[2]=0; }

__global__ void update_k(int* flags){
  if (!flags[0]){ flags[1] += 1; if (flags[2]==0) flags[0]=1; }
  flags[2] = 0;
}

__global__ __launch_bounds__(256)
void final_k(const float* __restrict__ buf1, float* __restrict__ out, const int* __restrict__ flags)
{
  const int i = blockIdx.x*256 + threadIdx.x;
  const int k = flags[1];
  if ((k & 1) && i < BSZ*NV) out[i] = buf1[i];
  if (i == 0) out[2*BSZ*NV] = (float)k;
}

__global__ void finalp_k(float* __restrict__ out, const int* __restrict__ flags)
{
  out[2*(size_t)BSZ*NV] = (float)flags[1];
}

// ---------------- host launch ----------------
extern "C" void kernel_launch(void* const* d_in, const int* in_sizes, int n_in,
                              void* d_out, int out_size, void* d_ws, size_t ws_size,
                              hipStream_t stream)
{
  const float* bp  = (const float*)d_in[0];
  const float* w1  = (const float*)d_in[1];
  const float* b1  = (const float*)d_in[2];
  const float* g1  = (const float*)d_in[3];
  const float* be1 = (const float*)d_in[4];
  const float* w2  = (const float*)d_in[5];
  const float* b2  = (const float*)d_in[6];
  const float* g2  = (const float*)d_in[7];
  const float* be2 = (const float*)d_in[8];
  const float* w3  = (const float*)d_in[9];
  const float* b3  = (const float*)d_in[10];
  const float* g3  = (const float*)d_in[11];
  const float* be3 = (const float*)d_in[12];
  const float* wo  = (const float*)d_in[13];
  const float* bo  = (const float*)d_in[14];
  const float* A   = (const float*)d_in[15];
  const float* Wz  = (const float*)d_in[16];
  const float* Wb  = (const float*)d_in[17];

  float* out  = (float*)d_out;
  float* z0   = out + (size_t)BSZ*NV;
  float* zbuf = out;                      // single z f32 buffer (freeze-safe)

  float* ws_f = (float*)d_ws;
  float* BiasM    = ws_f;                               // 1,048,576 f32
  float* pp       = BiasM + (size_t)BSZ*NV;             // 6 x 1,048,576 f32
  float* ppe      = pp + (size_t)6*BSZ*NV;              // 2 x 524,288 f32
  float* BiasATmB = ppe + (size_t)2*BSZ*MC;             // 524,288 f32
  float* eqpart16 = BiasATmB + (size_t)BSZ*MC;          // 32,768 f32
  float* ineqpart = eqpart16 + (size_t)16*MC;           // 65,536 f32
  int*   flags    = (int*)(ineqpart + (size_t)16*NV);   // 4 ints
  _Float16* Wzh = (_Float16*)(flags + 4);
  _Float16* Wzl = Wzh + (size_t)NV*NV;
  _Float16* Wbt = Wzl + (size_t)NV*NV;                  // [MC][NV]
  _Float16* rzh = Wbt + (size_t)MC*NV;
  _Float16* rzl = rzh + (size_t)BSZ*NV;
  const size_t need = (size_t)((char*)(rzl + (size_t)BSZ*NV) - (char*)d_ws);
  const bool fp16path = (ws_size >= need);
  // aliases (disjoint lifetimes):
  float* tmp1 = pp;                                     // MLP scratch, dead before fused
  float* tmp2 = pp + (size_t)BSZ*HID;
  _Float16* zh0 = (_Float16*)(pp + (size_t)4*BSZ*NV);   // z0 split; bootstrap writes pp[0..3] only
  _Float16* zl0 = zh0 + (size_t)BSZ*NV;

  const dim3 blk(256);

  if (fp16path){
    hipLaunchKernelGGL(init_k, dim3(1), dim3(1), 0, stream, flags);

    // ---- MLP (f32, one-time) ----
    hipLaunchKernelGGL((gemm_k<64,64,32,4,4,false,false,EPI_BIASRELU>), dim3(HID/64, BSZ/64), blk, 0, stream,
                       bp, MC, w1, HID, tmp1, MC, HID, b1, nullptr, 0, nullptr);
    hipLaunchKernelGGL(ln_k, dim3(BSZ), blk, 0, stream, tmp1, g1, be1);
    hipLaunchKernelGGL((gemm_k<64,64,32,4,4,false,false,EPI_BIASRELU>), dim3(HID/64, BSZ/64), blk, 0, stream,
                       tmp1, HID, w2, HID, tmp2, HID, HID, b2, nullptr, 0, nullptr);
    hipLaunchKernelGGL(ln_k, dim3(BSZ), blk, 0, stream, tmp2, g2, be2);
    hipLaunchKernelGGL((gemm_k<64,64,32,4,4,false,false,EPI_BIASRELU>), dim3(HID/64, BSZ/64), blk, 0, stream,
                       tmp2, HID, w3, HID, tmp1, HID, HID, b3, nullptr, 0, nullptr);
    hipLaunchKernelGGL(ln_k, dim3(BSZ), blk, 0, stream, tmp1, g3, be3);
    hipLaunchKernelGGL((gemm_k<64,64,32,4,4,false,false,EPI_BIAS>), dim3(NV/64, BSZ/64), blk, 0, stream,
                       tmp1, HID, wo, NV, z0, HID, NV, bo, nullptr, 0, nullptr);
    // Bias = b_primal @ WbProj^T
    hipLaunchKernelGGL((gemm_k<64,64,32,4,4,true,false,EPI_NONE>), dim3(NV/64, BSZ/64), blk, 0, stream,
                       bp, MC, Wb, MC, BiasM, MC, NV, nullptr, nullptr, 0, nullptr);
    // BiasATmB = Bias @ A^T - b
    hipLaunchKernelGGL((gemm_k<64,64,32,4,4,true,false,EPI_SUBMAT>), dim3(MC/64, BSZ/64), blk, 0, stream,
                       BiasM, NV, A, NV, BiasATmB, NV, MC, nullptr, bp, MC, nullptr);
    // one-time fp16 conversions
    hipLaunchKernelGGL(split_k, dim3((NV*(size_t)NV)/1024), blk, 0, stream, Wz, Wzh, Wzl, (int)((NV*(size_t)NV)/4));
    hipLaunchKernelGGL(trsplit_k, dim3(NV/64, MC/64), blk, 0, stream, Wb, Wbt);
    hipLaunchKernelGGL(split_k, dim3((BSZ*(size_t)NV)/1024), blk, 0, stream, z0, zh0, zl0, (int)((BSZ*(size_t)NV)/4));

    // bootstrap: z_init = Bias + z0 @ Wp (proj only, kz=4, writes pp[0..3])
    hipLaunchKernelGGL(fusedm_k, dim3(256), blk, 0, stream,
                       zh0, zl0, Wzh, Wzl, Wbt, pp, ppe, 4, flags);
    hipLaunchKernelGGL(combineN_k, dim3(NV/256, 16), blk, 0, stream,
                       pp, BiasM, zbuf, rzh, rzl, ineqpart, 4, flags);

    for (int j=1; j<=NITER; ++j){
      // proj partials for z_j + eq partials (eq(z_j) via identity), both from rz = P2(z_{j-1})
      hipLaunchKernelGGL(fusedm_k, dim3(448), blk, 0, stream,
                         rzh, rzl, Wzh, Wzl, Wbt, pp, ppe, 6, flags);
      hipLaunchKernelGGL(combineN_k, dim3(NV/256, 16), blk, 0, stream,
                         pp, BiasM, zbuf, rzh, rzl, ineqpart, 6, flags);
      hipLaunchKernelGGL(eqred2_k, dim3(MC/256, 16), blk, 0, stream,
                         ppe, BiasATmB, eqpart16, flags);
      hipLaunchKernelGGL(check3_k, dim3((MC + (NV-FREEN))/256), blk, 0, stream,
                         eqpart16, ineqpart, flags+2, flags);
      hipLaunchKernelGGL(update_k, dim3(1), dim3(1), 0, stream, flags);
    }
    hipLaunchKernelGGL(finalp_k, dim3(1), dim3(1), 0, stream, out, flags);
  } else {
    // fallback: proven f32 loop (independent layout)
    float* ftmp1 = ws_f;
    float* ftmp2 = ftmp1 + (size_t)BSZ*HID;
    float* fBias = ftmp2 + (size_t)BSZ*HID;
    float* fbuf1 = fBias + (size_t)BSZ*NV;
    float* feqp  = fbuf1 + (size_t)BSZ*NV;
    int*   ffl   = (int*)(feqp + 8*MC);

    hipLaunchKernelGGL(init_k, dim3(1), dim3(1), 0, stream, ffl);
    hipLaunchKernelGGL((gemm_k<64,64,32,4,4,false,false,EPI_BIASRELU>), dim3(HID/64, BSZ/64), blk, 0, stream,
                       bp, MC, w1, HID, ftmp1, MC, HID, b1, nullptr, 0, nullptr);
    hipLaunchKernelGGL(ln_k, dim3(BSZ), blk, 0, stream, ftmp1, g1, be1);
    hipLaunchKernelGGL((gemm_k<64,64,32,4,4,false,false,EPI_BIASRELU>), dim3(HID/64, BSZ/64), blk, 0, stream,
                       ftmp1, HID, w2, HID, ftmp2, HID, HID, b2, nullptr, 0, nullptr);
    hipLaunchKernelGGL(ln_k, dim3(BSZ), blk, 0, stream, ftmp2, g2, be2);
    hipLaunchKernelGGL((gemm_k<64,64,32,4,4,false,false,EPI_BIASRELU>), dim3(HID/64, BSZ/64), blk, 0, stream,
                       ftmp2, HID, w3, HID, ftmp1, HID, HID, b3, nullptr, 0, nullptr);
    hipLaunchKernelGGL(ln_k, dim3(BSZ), blk, 0, stream, ftmp1, g3, be3);
    hipLaunchKernelGGL((gemm_k<64,64,32,4,4,false,false,EPI_BIAS>), dim3(NV/64, BSZ/64), blk, 0, stream,
                       ftmp1, HID, wo, NV, z0, HID, NV, bo, nullptr, 0, nullptr);
    hipLaunchKernelGGL((gemm_k<64,64,32,4,4,true,false,EPI_NONE>), dim3(NV/64, BSZ/64), blk, 0, stream,
                       bp, MC, Wb, MC, fBias, MC, NV, nullptr, nullptr, 0, nullptr);
    hipLaunchKernelGGL((gemm_k<64,64,32,4,4,true,false,EPI_ADDMAT>), dim3(NV/64, BSZ/64), blk, 0, stream,
                       z0, NV, Wz, NV, out, NV, NV, nullptr, fBias, NV, nullptr);
    for (int j=1; j<=NITER; ++j){
      float* src = (j&1) ? out : fbuf1;
      float* dst = (j&1) ? fbuf1 : out;
      hipLaunchKernelGGL((gemm_k<64,64,32,4,4,true,true,EPI_ADDMAT>), dim3(NV/64, BSZ/64), blk, 0, stream,
                         src, NV, Wz, NV, dst, NV, NV, nullptr, fBias, NV, ffl);
      hipLaunchKernelGGL((gemm_k<32,64,32,2,4,true,false,EPI_EQ>), dim3(MC/64, BSZ/32), blk, 0, stream,
                         dst, NV, A, NV, feqp, NV, MC, nullptr, bp, MC, ffl);
      hipLaunchKernelGGL(check_k, dim3((MC + (NV-FREEN))/256), blk, 0, stream, feqp, dst, ffl+2, ffl, 8);
      hipLaunchKernelGGL(update_k, dim3(1), dim3(1), 0, stream, ffl);
    }
    hipLaunchKernelGGL(final_k, dim3((BSZ*NV)/256), blk, 0, stream, fbuf1, out, ffl);
  }

  (void)in_sizes; (void)n_in; (void)out_size; (void)ws_size;
}

// Round 7
// 4210.764 us; speedup vs baseline: 2.0181x; 1.0279x over previous
//
#include <hip/hip_runtime.h>
#include <math.h>

#define BSZ 256
#define NV  4096
#define MC  2048
#define HID 1024
#define FREEN 512
#define NITER 31
#define TOLF 1e-4f
#define EPSF 1e-6f
#define INV2048 4.8828125e-4f

typedef _Float16 half8 __attribute__((ext_vector_type(8)));
typedef _Float16 half4 __attribute__((ext_vector_type(4)));
typedef float f32x16 __attribute__((ext_vector_type(16)));

enum { EPI_NONE=0, EPI_BIASRELU=1, EPI_BIAS=2, EPI_ADDMAT=3, EPI_EQ=4, EPI_SUBMAT=5 };

// ---------------- f32 vector-ALU GEMM (fallback path only) ----------------
template<int BM,int BN,int BK,int TM,int TN,bool TB,bool RELUIN,int EPI>
__global__ __launch_bounds__(256)
void gemm_k(const float* __restrict__ X, int ldx,
            const float* __restrict__ W, int ldw,
            float* __restrict__ C,
            int K, int N,
            const float* __restrict__ bvec,
            const float* __restrict__ addm, int ldadd,
            const int* __restrict__ guard)
{
  if (guard && guard[0]) return;
  const int t = (int)threadIdx.x;
  const int m0 = (int)blockIdx.y*BM, n0 = (int)blockIdx.x*BN;
  __shared__ float As[BK][BM+4];
  __shared__ float Bs[BK][BN+4];
  constexpr int TX = BN/TN;
  const int tx = t % TX, ty = t / TX;
  constexpr int ALD = (BM*BK)/1024;
  constexpr int BLD = (BN*BK)/1024;
  float4 pa[ALD], pb[BLD];
  float acc[TM][TN];
  #pragma unroll
  for (int i=0;i<TM;i++)
    #pragma unroll
    for (int j=0;j<TN;j++) acc[i][j]=0.f;

  const int nk = K/BK;

  auto loadA = [&](int kt){
    const int k0 = kt*BK;
    const bool rl = RELUIN && (k0 >= FREEN);
    #pragma unroll
    for (int q=0;q<ALD;q++){
      const int idx = q*256 + t;
      const int r = idx/(BK/4), c4 = (idx%(BK/4))*4;
      float4 v = *reinterpret_cast<const float4*>(&X[(size_t)(m0+r)*ldx + k0 + c4]);
      if (rl){ v.x=fmaxf(v.x,0.f); v.y=fmaxf(v.y,0.f); v.z=fmaxf(v.z,0.f); v.w=fmaxf(v.w,0.f); }
      pa[q]=v;
    }
  };
  auto loadB = [&](int kt){
    const int k0 = kt*BK;
    #pragma unroll
    for (int q=0;q<BLD;q++){
      const int idx = q*256 + t;
      if (TB){
        const int r = idx/(BK/4), c4 = (idx%(BK/4))*4;
        pb[q] = *reinterpret_cast<const float4*>(&W[(size_t)(n0+r)*ldw + k0 + c4]);
      } else {
        const int r = idx/(BN/4), c4 = (idx%(BN/4))*4;
        pb[q] = *reinterpret_cast<const float4*>(&W[(size_t)(k0+r)*ldw + n0 + c4]);
      }
    }
  };
  auto stor = [&](){
    #pragma unroll
    for (int q=0;q<ALD;q++){
      const int idx = q*256 + t;
      const int r = idx/(BK/4), c4 = (idx%(BK/4))*4;
      As[c4+0][r]=pa[q].x; As[c4+1][r]=pa[q].y; As[c4+2][r]=pa[q].z; As[c4+3][r]=pa[q].w;
    }
    #pragma unroll
    for (int q=0;q<BLD;q++){
      const int idx = q*256 + t;
      if (TB){
        const int r = idx/(BK/4), c4 = (idx%(BK/4))*4;
        Bs[c4+0][r]=pb[q].x; Bs[c4+1][r]=pb[q].y; Bs[c4+2][r]=pb[q].z; Bs[c4+3][r]=pb[q].w;
      } else {
        const int r = idx/(BN/4), c4 = (idx%(BN/4))*4;
        *reinterpret_cast<float4*>(&Bs[r][c4]) = pb[q];
      }
    }
  };

  loadA(0); loadB(0);
  for (int kt=0; kt<nk; ++kt){
    __syncthreads();
    stor();
    __syncthreads();
    if (kt+1 < nk){ loadA(kt+1); loadB(kt+1); }
    #pragma unroll
    for (int kk=0; kk<BK; ++kk){
      float a[TM], b[TN];
      if constexpr (TM==4) *reinterpret_cast<float4*>(a) = *reinterpret_cast<const float4*>(&As[kk][ty*TM]);
      else                 *reinterpret_cast<float2*>(a) = *reinterpret_cast<const float2*>(&As[kk][ty*TM]);
      if constexpr (TN==4) *reinterpret_cast<float4*>(b) = *reinterpret_cast<const float4*>(&Bs[kk][tx*TN]);
      else                 *reinterpret_cast<float2*>(b) = *reinterpret_cast<const float2*>(&Bs[kk][tx*TN]);
      #pragma unroll
      for (int i=0;i<TM;i++)
        #pragma unroll
        for (int j=0;j<TN;j++)
          acc[i][j] = fmaf(a[i], b[j], acc[i][j]);
    }
  }

  if constexpr (EPI==EPI_EQ){
    float csum[TN];
    #pragma unroll
    for (int j=0;j<TN;j++) csum[j]=0.f;
    #pragma unroll
    for (int i=0;i<TM;i++){
      const int r = m0 + ty*TM + i;
      #pragma unroll
      for (int j=0;j<TN;j++){
        const int c = n0 + tx*TN + j;
        const float v = acc[i][j] - addm[(size_t)r*ldadd + c];
        csum[j] += fabsf(v);
      }
    }
    __syncthreads();
    float* red = &As[0][0];
    constexpr int RY = BM/TM;
    #pragma unroll
    for (int j=0;j<TN;j++) red[(tx*TN+j)*RY + ty] = csum[j];
    __syncthreads();
    if (t < BN){
      float s=0.f;
      #pragma unroll
      for (int y=0;y<RY;y++) s += red[t*RY + y];
      C[(size_t)blockIdx.y*N + n0 + t] = s;
    }
  } else {
    #pragma unroll
    for (int i=0;i<TM;i++){
      const int r = m0 + ty*TM + i;
      #pragma unroll
      for (int j=0;j<TN;j++){
        const int c = n0 + tx*TN + j;
        float v = acc[i][j];
        if constexpr (EPI==EPI_BIASRELU){ v += bvec[c]; v = fmaxf(v,0.f); }
        if constexpr (EPI==EPI_BIAS)    { v += bvec[c]; }
        if constexpr (EPI==EPI_ADDMAT)  { v += addm[(size_t)r*ldadd + c]; }
        if constexpr (EPI==EPI_SUBMAT)  { v -= addm[(size_t)r*ldadd + c]; }
        C[(size_t)r*N + c] = v;
      }
    }
  }
}

// ---------------- fp16x2 split helpers ----------------
__device__ __forceinline__ void split_f32(float v, _Float16& h, _Float16& l){
  float hf = 0.f;
  _Float16 hh = (_Float16)0.f;
  if (fabsf(v) >= 6.103515625e-05f) { hh = (_Float16)v; hf = (float)hh; }
  h = hh;
  l = (_Float16)((v - hf) * 2048.0f);
}

__global__ __launch_bounds__(256)
void split_k(const float* __restrict__ src, _Float16* __restrict__ h,
             _Float16* __restrict__ l, int n4)
{
  const int i = blockIdx.x*256 + threadIdx.x;
  if (i >= n4) return;
  const float4 v = *reinterpret_cast<const float4*>(&src[(size_t)i*4]);
  half4 hh, ll;
  _Float16 a, b;
  split_f32(v.x,a,b); hh.x=a; ll.x=b;
  split_f32(v.y,a,b); hh.y=a; ll.y=b;
  split_f32(v.z,a,b); hh.z=a; ll.z=b;
  split_f32(v.w,a,b); hh.w=a; ll.w=b;
  *reinterpret_cast<half4*>(&h[(size_t)i*4]) = hh;
  *reinterpret_cast<half4*>(&l[(size_t)i*4]) = ll;
}

// transpose-convert: W [NV][MC] f32 row-major -> Wt [MC][NV] fp16 (hi only)
__global__ __launch_bounds__(256)
void trsplit_k(const float* __restrict__ W, _Float16* __restrict__ Wt)
{
  __shared__ float ts[64][65];
  const int t = (int)threadIdx.x;
  const int i0 = (int)blockIdx.x*64;
  const int j0 = (int)blockIdx.y*64;
  const int rr = t >> 4, cc = (t & 15)*4;
  #pragma unroll
  for (int p=0;p<4;p++){
    const int r = p*16 + rr;
    const float4 v = *reinterpret_cast<const float4*>(&W[(size_t)(i0+r)*MC + j0 + cc]);
    ts[r][cc+0]=v.x; ts[r][cc+1]=v.y; ts[r][cc+2]=v.z; ts[r][cc+3]=v.w;
  }
  __syncthreads();
  #pragma unroll
  for (int p=0;p<4;p++){
    const int orow = p*16 + rr;
    half4 h;
    h.x = (_Float16)ts[cc+0][orow];
    h.y = (_Float16)ts[cc+1][orow];
    h.z = (_Float16)ts[cc+2][orow];
    h.w = (_Float16)ts[cc+3][orow];
    *reinterpret_cast<half4*>(&Wt[(size_t)(j0+orow)*NV + i0 + cc]) = h;
  }
}

// transpose + pair-split: W [R][C] f32 -> out [C][R] fp16 pair. grid (R/64, C/64)
__global__ __launch_bounds__(256)
void trsplit2_k(const float* __restrict__ W, _Float16* __restrict__ oh,
                _Float16* __restrict__ ol, int R, int C)
{
  __shared__ float ts[64][65];
  const int t = (int)threadIdx.x;
  const int i0 = (int)blockIdx.x*64;   // row in W
  const int j0 = (int)blockIdx.y*64;   // col in W
  const int rr = t >> 4, cc = (t & 15)*4;
  #pragma unroll
  for (int p=0;p<4;p++){
    const int r = p*16 + rr;
    const float4 v = *reinterpret_cast<const float4*>(&W[(size_t)(i0+r)*C + j0 + cc]);
    ts[r][cc+0]=v.x; ts[r][cc+1]=v.y; ts[r][cc+2]=v.z; ts[r][cc+3]=v.w;
  }
  __syncthreads();
  #pragma unroll
  for (int p=0;p<4;p++){
    const int orow = p*16 + rr;        // output row = W col j0+orow
    half4 h4, l4;
    _Float16 h, l;
    split_f32(ts[cc+0][orow], h, l); h4.x=h; l4.x=l;
    split_f32(ts[cc+1][orow], h, l); h4.y=h; l4.y=l;
    split_f32(ts[cc+2][orow], h, l); h4.z=h; l4.z=l;
    split_f32(ts[cc+3][orow], h, l); h4.w=h; l4.w=l;
    const size_t o = (size_t)(j0+orow)*R + i0 + cc;
    *reinterpret_cast<half4*>(&oh[o]) = h4;
    *reinterpret_cast<half4*>(&ol[o]) = l4;
  }
}

// ---------------- generic fp16x2 pair-GEMM (prologue) ----------------
// C_partial[kz] = (A @ B^T) over ext-K chunk. A [256][K] pair, B [N][K] pair (k-contig).
// ext-K = [0,K): Ah*Bl | [K,2K): Al*Bh | [2K,3K): Ah*Bh ; acc *= 1/2048 at ext==2K.
// Tile 128x128, BK=32, dbuf LDS, global_load_lds w16. grid (N/128, 2, kz).
__global__ __launch_bounds__(256)
void pairgemm_k(const _Float16* __restrict__ Ahg, const _Float16* __restrict__ Alg,
                const _Float16* __restrict__ Bhg, const _Float16* __restrict__ Blg,
                float* __restrict__ partial, int N, int K, int kzn,
                const int* __restrict__ guard)
{
  if (guard[0]) return;
  __shared__ _Float16 lds[2][8192];
  const int t = (int)threadIdx.x;
  const int lane = t & 63, wid = t >> 6;
  const int wr = wid >> 1, wc = wid & 1;
  const int ln = lane & 31, lg = lane >> 5;

  const int nt = (int)blockIdx.x, mt = (int)blockIdx.y, kz = (int)blockIdx.z;
  const int m0 = mt*128, n0 = nt*128;
  const int chunk = (3*K)/kzn;
  const int loExt = kz*chunk;
  const int nsteps = chunk/32;
  int ss = (2*K - loExt)/32;
  const int scaleStep = ss < 0 ? 0 : ss;

  f32x16 acc[2][2];
  #pragma unroll
  for (int fm=0;fm<2;fm++)
    #pragma unroll
    for (int fn=0;fn<2;fn++)
      #pragma unroll
      for (int r=0;r<16;r++) acc[fm][fn][r] = 0.f;

  auto stage = [&](int i, int buf){
    const int gext = loExt + i*32;
    const _Float16* aB; const _Float16* bB; int kk;
    if (gext < K)         { aB = Ahg; bB = Blg; kk = gext; }
    else if (gext < 2*K)  { aB = Alg; bB = Bhg; kk = gext - K; }
    else                  { aB = Ahg; bB = Bhg; kk = gext - 2*K; }
    _Float16* base = &lds[buf][0];
    const int r = (wid<<5) + (lane>>2);
    const int kadd = kk + ((lane&3)<<3);
    #pragma unroll
    for (int q=0;q<2;q++){
      const _Float16* ga = aB + (size_t)(m0 + r + q*16)*K + kadd;
      __builtin_amdgcn_global_load_lds(
        (const __attribute__((address_space(1))) void*)ga,
        (__attribute__((address_space(3))) void*)(base + wid*1024 + q*512), 16, 0, 0);
      const _Float16* gb = bB + (size_t)(n0 + r + q*16)*K + kadd;
      __builtin_amdgcn_global_load_lds(
        (const __attribute__((address_space(1))) void*)gb,
        (__attribute__((address_space(3))) void*)(base + 4096 + wid*1024 + q*512), 16, 0, 0);
    }
  };

  int cur = 0;
  stage(0, 0);
  __syncthreads();
  for (int i=0; i<nsteps; ++i){
    if (i+1 < nsteps) stage(i+1, cur^1);
    const _Float16* As = &lds[cur][0];
    const _Float16* Bs = &lds[cur][4096];
    half8 a[2][2], b[2][2];
    #pragma unroll
    for (int fm=0; fm<2; ++fm){
      const int row = wr*64 + fm*32 + ln;
      #pragma unroll
      for (int ks=0; ks<2; ++ks)
        a[fm][ks] = *reinterpret_cast<const half8*>(&As[row*32 + lg*8 + ks*16]);
    }
    #pragma unroll
    for (int fn=0; fn<2; ++fn){
      const int row = wc*64 + fn*32 + ln;
      #pragma unroll
      for (int ks=0; ks<2; ++ks)
        b[fn][ks] = *reinterpret_cast<const half8*>(&Bs[row*32 + lg*8 + ks*16]);
    }
    if (i == scaleStep){
      #pragma unroll
      for (int fm=0;fm<2;fm++)
        #pragma unroll
        for (int fn=0;fn<2;fn++)
          #pragma unroll
          for (int r=0;r<16;r++) acc[fm][fn][r] *= INV2048;
    }
    #pragma unroll
    for (int ks=0; ks<2; ++ks)
      #pragma unroll
      for (int fm=0; fm<2; ++fm)
        #pragma unroll
        for (int fn=0; fn<2; ++fn)
          acc[fm][fn] = __builtin_amdgcn_mfma_f32_32x32x16_f16(a[fm][ks], b[fn][ks], acc[fm][fn], 0, 0, 0);
    __syncthreads();
    cur ^= 1;
  }
  if (scaleStep >= nsteps){
    #pragma unroll
    for (int fm=0;fm<2;fm++)
      #pragma unroll
      for (int fn=0;fn<2;fn++)
        #pragma unroll
        for (int r=0;r<16;r++) acc[fm][fn][r] *= INV2048;
  }

  float* __restrict__ dst = partial + (size_t)kz*BSZ*N;
  #pragma unroll
  for (int fm=0; fm<2; ++fm)
    #pragma unroll
    for (int fn=0; fn<2; ++fn)
      #pragma unroll
      for (int r=0; r<16; ++r){
        const int row = (r&3) + 8*(r>>2) + 4*lg;
        const int gm = m0 + wr*64 + fm*32 + row;
        const int gn = n0 + wc*64 + fn*32 + ln;
        dst[(size_t)gm*N + gn] = acc[fm][fn][r];
      }
}

// sum of kz partials + flexible epilogue. grid (N/256, 16)
__global__ __launch_bounds__(256)
void sumn_k(const float* __restrict__ partial, int ng, int N,
            const float* __restrict__ bvec, const float* __restrict__ subm,
            int relu, float* __restrict__ outf,
            _Float16* __restrict__ oh, _Float16* __restrict__ ol,
            const int* __restrict__ guard)
{
  if (guard[0]) return;
  const int c = blockIdx.x*256 + threadIdx.x;
  const int rb = blockIdx.y;
  const size_t SZ = (size_t)BSZ*N;
  for (int r=0; r<16; ++r){
    const size_t idx = (size_t)(rb*16+r)*N + c;
    float s = 0.f;
    for (int g=0; g<ng; ++g) s += partial[(size_t)g*SZ + idx];
    if (bvec) s += bvec[c];
    if (subm) s -= subm[idx];
    if (relu) s = fmaxf(s, 0.f);
    outf[idx] = s;
    if (oh){
      _Float16 h, l; split_f32(s, h, l);
      oh[idx] = h; ol[idx] = l;
    }
  }
}

// ---------------- fused loop MFMA kernel (proven round-6 structure) ----------------
__global__ __launch_bounds__(256)
void fusedm_k(const _Float16* __restrict__ Ahg, const _Float16* __restrict__ Alg,
              const _Float16* __restrict__ Wzh, const _Float16* __restrict__ Wzl,
              const _Float16* __restrict__ Wbt,
              float* __restrict__ pp, float* __restrict__ ppe,
              int projKz, const int* __restrict__ guard)
{
  if (guard[0]) return;
  __shared__ _Float16 lds[2][8192];
  const int t = (int)threadIdx.x;
  const int lane = t & 63, wid = t >> 6;
  const int wr = wid >> 1, wc = wid & 1;
  const int ln = lane & 31, lg = lane >> 5;

  const int bid = (int)blockIdx.x;
  const int nProj = 64*projKz;
  const bool is_eq = bid >= nProj;
  int kz, mt, nt, nsteps, scaleStep, loExt;
  if (!is_eq){
    kz = bid % projKz;
    mt = (bid / projKz) & 1;
    nt = bid / (2*projKz);
    const int chunk = 12288 / projKz;
    loExt = kz * chunk;
    nsteps = chunk / 32;
    const int ss = (8192 - loExt) / 32;
    scaleStep = ss < 0 ? 0 : ss;
  } else {
    const int e = bid - nProj;
    kz = e & 1; mt = (e>>1)&1; nt = e>>2;
    loExt = 0; nsteps = 64; scaleStep = -1;
  }
  const int m0 = mt*128, n0 = nt*128;

  f32x16 acc[2][2];
  #pragma unroll
  for (int fm=0;fm<2;fm++)
    #pragma unroll
    for (int fn=0;fn<2;fn++)
      #pragma unroll
      for (int r=0;r<16;r++) acc[fm][fn][r] = 0.f;

  auto stage = [&](int i, int buf){
    const _Float16* aB; const _Float16* bB; int kk;
    if (is_eq){
      aB = Ahg; bB = Wbt; kk = kz*2048 + i*32;
    } else {
      const int gext = loExt + i*32;
      if (gext < 4096)      { aB = Ahg; bB = Wzl; kk = gext; }
      else if (gext < 8192) { aB = Alg; bB = Wzh; kk = gext - 4096; }
      else                  { aB = Ahg; bB = Wzh; kk = gext - 8192; }
    }
    _Float16* base = &lds[buf][0];
    const int r = (wid<<5) + (lane>>2);
    const int kadd = kk + ((lane&3)<<3);
    #pragma unroll
    for (int q=0;q<2;q++){
      const _Float16* ga = aB + (size_t)(m0 + r + q*16)*NV + kadd;
      __builtin_amdgcn_global_load_lds(
        (const __attribute__((address_space(1))) void*)ga,
        (__attribute__((address_space(3))) void*)(base + wid*1024 + q*512), 16, 0, 0);
      const _Float16* gb = bB + (size_t)(n0 + r + q*16)*NV + kadd;
      __builtin_amdgcn_global_load_lds(
        (const __attribute__((address_space(1))) void*)gb,
        (__attribute__((address_space(3))) void*)(base + 4096 + wid*1024 + q*512), 16, 0, 0);
    }
  };

  int cur = 0;
  stage(0, 0);
  __syncthreads();
  for (int i=0; i<nsteps; ++i){
    if (i+1 < nsteps) stage(i+1, cur^1);
    const _Float16* As = &lds[cur][0];
    const _Float16* Bs = &lds[cur][4096];
    half8 a[2][2], b[2][2];
    #pragma unroll
    for (int fm=0; fm<2; ++fm){
      const int row = wr*64 + fm*32 + ln;
      #pragma unroll
      for (int ks=0; ks<2; ++ks)
        a[fm][ks] = *reinterpret_cast<const half8*>(&As[row*32 + lg*8 + ks*16]);
    }
    #pragma unroll
    for (int fn=0; fn<2; ++fn){
      const int row = wc*64 + fn*32 + ln;
      #pragma unroll
      for (int ks=0; ks<2; ++ks)
        b[fn][ks] = *reinterpret_cast<const half8*>(&Bs[row*32 + lg*8 + ks*16]);
    }
    if (!is_eq && i == scaleStep){
      #pragma unroll
      for (int fm=0;fm<2;fm++)
        #pragma unroll
        for (int fn=0;fn<2;fn++)
          #pragma unroll
          for (int r=0;r<16;r++) acc[fm][fn][r] *= INV2048;
    }
    #pragma unroll
    for (int ks=0; ks<2; ++ks)
      #pragma unroll
      for (int fm=0; fm<2; ++fm)
        #pragma unroll
        for (int fn=0; fn<2; ++fn)
          acc[fm][fn] = __builtin_amdgcn_mfma_f32_32x32x16_f16(a[fm][ks], b[fn][ks], acc[fm][fn], 0, 0, 0);
    __syncthreads();
    cur ^= 1;
  }
  if (!is_eq && scaleStep >= nsteps){
    #pragma unroll
    for (int fm=0;fm<2;fm++)
      #pragma unroll
      for (int fn=0;fn<2;fn++)
        #pragma unroll
        for (int r=0;r<16;r++) acc[fm][fn][r] *= INV2048;
  }

  if (is_eq){
    float* __restrict__ dst = ppe + (size_t)kz*BSZ*MC;
    #pragma unroll
    for (int fm=0; fm<2; ++fm)
      #pragma unroll
      for (int fn=0; fn<2; ++fn)
        #pragma unroll
        for (int r=0; r<16; ++r){
          const int row = (r&3) + 8*(r>>2) + 4*lg;
          const int gm = m0 + wr*64 + fm*32 + row;
          const int gn = n0 + wc*64 + fn*32 + ln;
          dst[(size_t)gm*MC + gn] = acc[fm][fn][r];
        }
  } else {
    float* __restrict__ dst = pp + (size_t)kz*BSZ*NV;
    #pragma unroll
    for (int fm=0; fm<2; ++fm)
      #pragma unroll
      for (int fn=0; fn<2; ++fn)
        #pragma unroll
        for (int r=0; r<16; ++r){
          const int row = (r&3) + 8*(r>>2) + 4*lg;
          const int gm = m0 + wr*64 + fm*32 + row;
          const int gn = n0 + wc*64 + fn*32 + ln;
          dst[(size_t)gm*NV + gn] = acc[fm][fn][r];
        }
  }
}

// combine: z = sum_ng(pp) + Bias -> z f32, rz pair = split(P2(z)), ineq partials
__global__ __launch_bounds__(256)
void combineN_k(const float* __restrict__ pp, const float* __restrict__ BiasM,
                float* __restrict__ zout, _Float16* __restrict__ rzh,
                _Float16* __restrict__ rzl, float* __restrict__ ineqpart,
                int ng, const int* __restrict__ guard)
{
  if (guard[0]) return;
  const int c = blockIdx.x*256 + threadIdx.x;
  const int rb = blockIdx.y;
  const size_t SZ = (size_t)BSZ*NV;
  float acc = 0.f;
  for (int r=0; r<16; ++r){
    const size_t idx = (size_t)(rb*16+r)*NV + c;
    float z = BiasM[idx];
    for (int g=0; g<ng; ++g) z += pp[(size_t)g*SZ + idx];
    zout[idx] = z;
    const float rz = (c >= FREEN) ? fmaxf(z, 0.f) : z;
    _Float16 h, l; split_f32(rz, h, l);
    rzh[idx] = h; rzl[idx] = l;
    acc += fmaxf(-z, 0.f);
  }
  ineqpart[(size_t)rb*NV + c] = acc;
}

__global__ __launch_bounds__(256)
void eqred2_k(const float* __restrict__ ppe, const float* __restrict__ BiasATmB,
              float* __restrict__ eqpart16, const int* __restrict__ guard)
{
  if (guard[0]) return;
  const int c = blockIdx.x*256 + threadIdx.x;
  const int rb = blockIdx.y;
  const size_t SE = (size_t)BSZ*MC;
  float s = 0.f;
  for (int r=0; r<16; ++r){
    const size_t idx = (size_t)(rb*16+r)*MC + c;
    const float v = BiasATmB[idx] + EPSF*(ppe[idx] + ppe[SE+idx]);
    s += fabsf(v);
  }
  eqpart16[(size_t)rb*MC + c] = s;
}

__global__ __launch_bounds__(256)
void check3_k(const float* __restrict__ eqpart16, const float* __restrict__ ineqpart,
              int* __restrict__ viol, const int* __restrict__ done)
{
  if (done[0]) return;
  const int id = blockIdx.x*256 + threadIdx.x;
  bool bad;
  if (id < MC){
    float s = 0.f;
    #pragma unroll
    for (int g=0; g<16; g++) s += eqpart16[(size_t)g*MC + id];
    bad = (s*(1.f/(float)BSZ) > TOLF);
  } else {
    const int c = FREEN + (id - MC);
    float s = 0.f;
    #pragma unroll
    for (int g=0; g<16; g++) s += ineqpart[(size_t)g*NV + c];
    bad = (s*(1.f/(float)BSZ) > TOLF);
  }
  if (bad) atomicAdd(viol, 1);
}

// ---------------- LayerNorm ----------------
__global__ __launch_bounds__(256)
void ln_k(float* __restrict__ x, const float* __restrict__ g, const float* __restrict__ b)
{
  const int row = blockIdx.x, t = threadIdx.x;
  float4 v = *reinterpret_cast<const float4*>(&x[(size_t)row*HID + t*4]);
  __shared__ float sm[256];
  sm[t] = v.x+v.y+v.z+v.w;
  __syncthreads();
  for (int st=128; st>0; st>>=1){ if (t<st) sm[t]+=sm[t+st]; __syncthreads(); }
  const float mu = sm[0]*(1.f/(float)HID);
  __syncthreads();
  const float dx=v.x-mu, dy=v.y-mu, dz=v.z-mu, dw=v.w-mu;
  sm[t] = dx*dx+dy*dy+dz*dz+dw*dw;
  __syncthreads();
  for (int st=128; st>0; st>>=1){ if (t<st) sm[t]+=sm[t+st]; __syncthreads(); }
  const float inv = 1.f/sqrtf(sm[0]*(1.f/(float)HID) + 1e-5f);
  const int c = t*4;
  const float4 gv = *reinterpret_cast<const float4*>(&g[c]);
  const float4 bv = *reinterpret_cast<const float4*>(&b[c]);
  float4 o;
  o.x = dx*inv*gv.x + bv.x; o.y = dy*inv*gv.y + bv.y;
  o.z = dz*inv*gv.z + bv.z; o.w = dw*inv*gv.w + bv.w;
  *reinterpret_cast<float4*>(&x[(size_t)row*HID + c]) = o;
}

// ---------------- flags / fallback machinery ----------------
__global__ __launch_bounds__(256)
void check_k(const float* __restrict__ eqpart, const float* __restrict__ znew,
             int* __restrict__ viol, const int* __restrict__ done, int ngroups)
{
  if (done[0]) return;
  const int id = blockIdx.x*256 + threadIdx.x;
  bool bad;
  if (id < MC){
    float s = 0.f;
    for (int g=0; g<ngroups; g++) s += eqpart[g*MC + id];
    bad = (s*(1.f/(float)BSZ) > TOLF);
  } else {
    const int c = FREEN + (id - MC);
    float s = 0.f;
    for (int r=0; r<BSZ; r++){
      const float v = znew[(size_t)r*NV + c];
      s += (v < 0.f) ? -v : 0.f;
    }
    bad = (s*(1.f/(float)BSZ) > TOLF);
  }
  if (bad) atomicAdd(viol, 1);
}

__global__ void init_k(int* flags){ flags[0]=0; flags[1]=0; flags[2]=0; }

__global__ void update_k(int* flags){
  if (!flags[0]){ flags[1] += 1; if (flags[2]==0) flags[0]=1; }
  flags[2] = 0;
}

__global__ __launch_bounds__(256)
void final_k(const float* __restrict__ buf1, float* __restrict__ out, const int* __restrict__ flags)
{
  const int i = blockIdx.x*256 + threadIdx.x;
  const int k = flags[1];
  if ((k & 1) && i < BSZ*NV) out[i] = buf1[i];
  if (i == 0) out[2*BSZ*NV] = (float)k;
}

__global__ void finalp_k(float* __restrict__ out, const int* __restrict__ flags)
{
  out[2*(size_t)BSZ*NV] = (float)flags[1];
}

// ---------------- host launch ----------------
extern "C" void kernel_launch(void* const* d_in, const int* in_sizes, int n_in,
                              void* d_out, int out_size, void* d_ws, size_t ws_size,
                              hipStream_t stream)
{
  const float* bp  = (const float*)d_in[0];
  const float* w1  = (const float*)d_in[1];
  const float* b1  = (const float*)d_in[2];
  const float* g1  = (const float*)d_in[3];
  const float* be1 = (const float*)d_in[4];
  const float* w2  = (const float*)d_in[5];
  const float* b2  = (const float*)d_in[6];
  const float* g2  = (const float*)d_in[7];
  const float* be2 = (const float*)d_in[8];
  const float* w3  = (const float*)d_in[9];
  const float* b3  = (const float*)d_in[10];
  const float* g3  = (const float*)d_in[11];
  const float* be3 = (const float*)d_in[12];
  const float* wo  = (const float*)d_in[13];
  const float* bo  = (const float*)d_in[14];
  const float* A   = (const float*)d_in[15];
  const float* Wz  = (const float*)d_in[16];
  const float* Wb  = (const float*)d_in[17];

  float* out  = (float*)d_out;
  float* z0   = out + (size_t)BSZ*NV;
  float* zbuf = out;

  float* ws_f = (float*)d_ws;
  float* BiasM    = ws_f;                               // 4MB
  float* pp       = BiasM + (size_t)BSZ*NV;             // 24MB (6 partials)
  float* ppe      = pp + (size_t)6*BSZ*NV;              // 4MB
  float* BiasATmB = ppe + (size_t)2*BSZ*MC;             // 2MB
  float* eqpart16 = BiasATmB + (size_t)BSZ*MC;          // 128KB
  float* ineqpart = eqpart16 + (size_t)16*MC;           // 256KB
  int*   flags    = (int*)(ineqpart + (size_t)16*NV);   // 4 ints
  _Float16* Wzh = (_Float16*)(flags + 4);               // 32MB
  _Float16* Wzl = Wzh + (size_t)NV*NV;                  // 32MB
  _Float16* Wbt = Wzl + (size_t)NV*NV;                  // 16MB
  _Float16* rzh = Wbt + (size_t)MC*NV;                  // 2MB
  _Float16* rzl = rzh + (size_t)BSZ*NV;                 // 2MB
  const size_t need = (size_t)((char*)(rzl + (size_t)BSZ*NV) - (char*)d_ws);
  const bool fp16path = (ws_size >= need);

  // prologue scratch aliases inside the (not-yet-split) Wz pair region (64MB):
  _Float16* PBh = Wzh;                                  // B-pair slot hi (up to 16MB)
  _Float16* PBl = Wzh + (size_t)8*1024*1024;            // B-pair slot lo (at +16MB)
  _Float16* bph = Wzl;                                  // bp pair (2MB)
  _Float16* bpl = bph + (size_t)BSZ*MC;
  float*    hbuf = (float*)(bpl + (size_t)BSZ*MC);      // h f32 (1MB)
  _Float16* hph = (_Float16*)(hbuf + (size_t)BSZ*HID);  // h pair (1MB)
  _Float16* hpl = hph + (size_t)BSZ*HID;
  _Float16* Bsh = hpl + (size_t)BSZ*HID;                // Bias pair (4MB)
  _Float16* Bsl = Bsh + (size_t)BSZ*NV;
  _Float16* zh0 = rzh;                                  // z0 pair borrows rz buffers
  _Float16* zl0 = rzl;

  const dim3 blk(256);

  if (fp16path){
    hipLaunchKernelGGL(init_k, dim3(1), dim3(1), 0, stream, flags);

    // ---- MLP via pair-MFMA ----
    hipLaunchKernelGGL(split_k, dim3((BSZ*(size_t)MC)/1024), blk, 0, stream, bp, bph, bpl, (int)((BSZ*(size_t)MC)/4));
    // g1: [256,2048]@[2048,1024]
    hipLaunchKernelGGL(trsplit2_k, dim3(MC/64, HID/64), blk, 0, stream, w1, PBh, PBl, MC, HID);
    hipLaunchKernelGGL(pairgemm_k, dim3(HID/128, 2, 4), blk, 0, stream,
                       bph, bpl, PBh, PBl, pp, HID, MC, 4, flags);
    hipLaunchKernelGGL(sumn_k, dim3(HID/256, 16), blk, 0, stream,
                       pp, 4, HID, b1, nullptr, 1, hbuf, (_Float16*)nullptr, (_Float16*)nullptr, flags);
    hipLaunchKernelGGL(ln_k, dim3(BSZ), blk, 0, stream, hbuf, g1, be1);
    hipLaunchKernelGGL(split_k, dim3((BSZ*(size_t)HID)/1024), blk, 0, stream, hbuf, hph, hpl, (int)((BSZ*(size_t)HID)/4));
    // g2
    hipLaunchKernelGGL(trsplit2_k, dim3(HID/64, HID/64), blk, 0, stream, w2, PBh, PBl, HID, HID);
    hipLaunchKernelGGL(pairgemm_k, dim3(HID/128, 2, 4), blk, 0, stream,
                       hph, hpl, PBh, PBl, pp, HID, HID, 4, flags);
    hipLaunchKernelGGL(sumn_k, dim3(HID/256, 16), blk, 0, stream,
                       pp, 4, HID, b2, nullptr, 1, hbuf, (_Float16*)nullptr, (_Float16*)nullptr, flags);
    hipLaunchKernelGGL(ln_k, dim3(BSZ), blk, 0, stream, hbuf, g2, be2);
    hipLaunchKernelGGL(split_k, dim3((BSZ*(size_t)HID)/1024), blk, 0, stream, hbuf, hph, hpl, (int)((BSZ*(size_t)HID)/4));
    // g3
    hipLaunchKernelGGL(trsplit2_k, dim3(HID/64, HID/64), blk, 0, stream, w3, PBh, PBl, HID, HID);
    hipLaunchKernelGGL(pairgemm_k, dim3(HID/128, 2, 4), blk, 0, stream,
                       hph, hpl, PBh, PBl, pp, HID, HID, 4, flags);
    hipLaunchKernelGGL(sumn_k, dim3(HID/256, 16), blk, 0, stream,
                       pp, 4, HID, b3, nullptr, 1, hbuf, (_Float16*)nullptr, (_Float16*)nullptr, flags);
    hipLaunchKernelGGL(ln_k, dim3(BSZ), blk, 0, stream, hbuf, g3, be3);
    hipLaunchKernelGGL(split_k, dim3((BSZ*(size_t)HID)/1024), blk, 0, stream, hbuf, hph, hpl, (int)((BSZ*(size_t)HID)/4));
    // z0 = h3 @ wo + bo  -> d_out z0 + pair (borrowing rz buffers)
    hipLaunchKernelGGL(trsplit2_k, dim3(HID/64, NV/64), blk, 0, stream, wo, PBh, PBl, HID, NV);
    hipLaunchKernelGGL(pairgemm_k, dim3(NV/128, 2, 4), blk, 0, stream,
                       hph, hpl, PBh, PBl, pp, NV, HID, 4, flags);
    hipLaunchKernelGGL(sumn_k, dim3(NV/256, 16), blk, 0, stream,
                       pp, 4, NV, bo, nullptr, 0, z0, zh0, zl0, flags);
    // Bias = bp @ WbProj^T  (B = WbProj native [NV][MC] k-contig)
    hipLaunchKernelGGL(split_k, dim3((NV*(size_t)MC)/1024), blk, 0, stream, Wb, PBh, PBl, (int)((NV*(size_t)MC)/4));
    hipLaunchKernelGGL(pairgemm_k, dim3(NV/128, 2, 4), blk, 0, stream,
                       bph, bpl, PBh, PBl, pp, NV, MC, 4, flags);
    hipLaunchKernelGGL(sumn_k, dim3(NV/256, 16), blk, 0, stream,
                       pp, 4, NV, nullptr, nullptr, 0, BiasM, Bsh, Bsl, flags);
    // BiasATmB = Bias @ A^T - bp  (B = A native [MC][NV] k-contig)
    hipLaunchKernelGGL(split_k, dim3((MC*(size_t)NV)/1024), blk, 0, stream, A, PBh, PBl, (int)((MC*(size_t)NV)/4));
    hipLaunchKernelGGL(pairgemm_k, dim3(MC/128, 2, 4), blk, 0, stream,
                       Bsh, Bsl, PBh, PBl, pp, MC, NV, 4, flags);
    hipLaunchKernelGGL(sumn_k, dim3(MC/256, 16), blk, 0, stream,
                       pp, 4, MC, nullptr, bp, 0, BiasATmB, (_Float16*)nullptr, (_Float16*)nullptr, flags);
    // loop constants (after all prologue scratch use: overwrites the alias region)
    hipLaunchKernelGGL(trsplit_k, dim3(NV/64, MC/64), blk, 0, stream, Wb, Wbt);
    hipLaunchKernelGGL(split_k, dim3((NV*(size_t)NV)/1024), blk, 0, stream, Wz, Wzh, Wzl, (int)((NV*(size_t)NV)/4));

    // bootstrap: z_init = Bias + z0 @ Wp
    hipLaunchKernelGGL(fusedm_k, dim3(256), blk, 0, stream,
                       zh0, zl0, Wzh, Wzl, Wbt, pp, ppe, 4, flags);
    hipLaunchKernelGGL(combineN_k, dim3(NV/256, 16), blk, 0, stream,
                       pp, BiasM, zbuf, rzh, rzl, ineqpart, 4, flags);

    for (int j=1; j<=NITER; ++j){
      hipLaunchKernelGGL(fusedm_k, dim3(448), blk, 0, stream,
                         rzh, rzl, Wzh, Wzl, Wbt, pp, ppe, 6, flags);
      hipLaunchKernelGGL(combineN_k, dim3(NV/256, 16), blk, 0, stream,
                         pp, BiasM, zbuf, rzh, rzl, ineqpart, 6, flags);
      hipLaunchKernelGGL(eqred2_k, dim3(MC/256, 16), blk, 0, stream,
                         ppe, BiasATmB, eqpart16, flags);
      hipLaunchKernelGGL(check3_k, dim3((MC + (NV-FREEN))/256), blk, 0, stream,
                         eqpart16, ineqpart, flags+2, flags);
      hipLaunchKernelGGL(update_k, dim3(1), dim3(1), 0, stream, flags);
    }
    hipLaunchKernelGGL(finalp_k, dim3(1), dim3(1), 0, stream, out, flags);
  } else {
    // fallback: proven f32 loop
    float* ftmp1 = ws_f;
    float* ftmp2 = ftmp1 + (size_t)BSZ*HID;
    float* fBias = ftmp2 + (size_t)BSZ*HID;
    float* fbuf1 = fBias + (size_t)BSZ*NV;
    float* feqp  = fbuf1 + (size_t)BSZ*NV;
    int*   ffl   = (int*)(feqp + 8*MC);

    hipLaunchKernelGGL(init_k, dim3(1), dim3(1), 0, stream, ffl);
    hipLaunchKernelGGL((gemm_k<64,64,32,4,4,false,false,EPI_BIASRELU>), dim3(HID/64, BSZ/64), blk, 0, stream,
                       bp, MC, w1, HID, ftmp1, MC, HID, b1, nullptr, 0, nullptr);
    hipLaunchKernelGGL(ln_k, dim3(BSZ), blk, 0, stream, ftmp1, g1, be1);
    hipLaunchKernelGGL((gemm_k<64,64,32,4,4,false,false,EPI_BIASRELU>), dim3(HID/64, BSZ/64), blk, 0, stream,
                       ftmp1, HID, w2, HID, ftmp2, HID, HID, b2, nullptr, 0, nullptr);
    hipLaunchKernelGGL(ln_k, dim3(BSZ), blk, 0, stream, ftmp2, g2, be2);
    hipLaunchKernelGGL((gemm_k<64,64,32,4,4,false,false,EPI_BIASRELU>), dim3(HID/64, BSZ/64), blk, 0, stream,
                       ftmp2, HID, w3, HID, ftmp1, HID, HID, b3, nullptr, 0, nullptr);
    hipLaunchKernelGGL(ln_k, dim3(BSZ), blk, 0, stream, ftmp1, g3, be3);
    hipLaunchKernelGGL((gemm_k<64,64,32,4,4,false,false,EPI_BIAS>), dim3(NV/64, BSZ/64), blk, 0, stream,
                       ftmp1, HID, wo, NV, z0, HID, NV, bo, nullptr, 0, nullptr);
    hipLaunchKernelGGL((gemm_k<64,64,32,4,4,true,false,EPI_NONE>), dim3(NV/64, BSZ/64), blk, 0, stream,
                       bp, MC, Wb, MC, fBias, MC, NV, nullptr, nullptr, 0, nullptr);
    hipLaunchKernelGGL((gemm_k<64,64,32,4,4,true,false,EPI_ADDMAT>), dim3(NV/64, BSZ/64), blk, 0, stream,
                       z0, NV, Wz, NV, out, NV, NV, nullptr, fBias, NV, nullptr);
    for (int j=1; j<=NITER; ++j){
      float* src = (j&1) ? out : fbuf1;
      float* dst = (j&1) ? fbuf1 : out;
      hipLaunchKernelGGL((gemm_k<64,64,32,4,4,true,true,EPI_ADDMAT>), dim3(NV/64, BSZ/64), blk, 0, stream,
                         src, NV, Wz, NV, dst, NV, NV, nullptr, fBias, NV, ffl);
      hipLaunchKernelGGL((gemm_k<32,64,32,2,4,true,false,EPI_EQ>), dim3(MC/64, BSZ/32), blk, 0, stream,
                         dst, NV, A, NV, feqp, NV, MC, nullptr, bp, MC, ffl);
      hipLaunchKernelGGL(check_k, dim3((MC + (NV-FREEN))/256), blk, 0, stream, feqp, dst, ffl+2, ffl, 8);
      hipLaunchKernelGGL(update_k, dim3(1), dim3(1), 0, stream, ffl);
    }
    hipLaunchKernelGGL(final_k, dim3((BSZ*NV)/256), blk, 0, stream, fbuf1, out, ffl);
  }

  (void)in_sizes; (void)n_in; (void)out_size; (void)ws_size;
}